// Round 1
// baseline (4674.528 us; speedup 1.0000x reference)
//
#include <hip/hip_runtime.h>
#include <hip/hip_bf16.h>

#define B 8
#define S 1024
#define E 1024
#define H 16
#define HD 64

typedef unsigned short u16;
typedef unsigned int u32;
typedef unsigned long long u64;

__device__ __forceinline__ float bf2f(u16 u) {
    union { u32 i; float f; } x; x.i = ((u32)u) << 16; return x.f;
}
__device__ __forceinline__ u16 f2bf(float f) {
    union { float f; u32 i; } x; x.f = f;
    u32 r = x.i + 0x7FFFu + ((x.i >> 16) & 1u);
    return (u16)(r >> 16);
}

// ---------------------------------------------------------------------------
// GEMM: C[m,n] = sum_k A[m,k] * W[n,k] + bias[n]
// A: fp32 (MODE 0, x) or bf16 (MODE 1, o). W fp32 [N][1024].
// MODE 0: scatter C as bf16 into q/k/v in [B,H,S,64] layout.
// MODE 1: write C fp32 [M][1024].
// Tile 64(M) x 128(N), K-step 32, 256 threads, 4x8 acc per thread.
// ---------------------------------------------------------------------------
template <int MODE>
__global__ __launch_bounds__(256) void gemm_kernel(
    const float* __restrict__ Af, const u16* __restrict__ Ab,
    const float* __restrict__ Bw, const float* __restrict__ bias,
    float* __restrict__ outf, u16* __restrict__ qb, u16* __restrict__ kb,
    u16* __restrict__ vb) {
    __shared__ float As[64][36];
    __shared__ float Bs[128][36];
    const int t = threadIdx.x;
    const int m0 = blockIdx.x * 64;
    const int n0 = blockIdx.y * 128;
    const int mi = (t & 15) * 4;
    const int nj = (t >> 4) * 8;
    float acc[4][8];
#pragma unroll
    for (int j = 0; j < 4; ++j)
#pragma unroll
        for (int jj = 0; jj < 8; ++jj) acc[j][jj] = 0.f;

    for (int k0 = 0; k0 < 1024; k0 += 32) {
        __syncthreads();
#pragma unroll
        for (int i = 0; i < 2; ++i) {
            int id = t + i * 256;
            int m = id >> 3, kq = (id & 7) * 4;
            float4 v;
            if (MODE == 0) {
                v = *(const float4*)(Af + (size_t)(m0 + m) * 1024 + k0 + kq);
            } else {
                ushort4 u = *(const ushort4*)(Ab + (size_t)(m0 + m) * 1024 + k0 + kq);
                v = make_float4(bf2f(u.x), bf2f(u.y), bf2f(u.z), bf2f(u.w));
            }
            *(float4*)&As[m][kq] = v;
        }
#pragma unroll
        for (int i = 0; i < 4; ++i) {
            int id = t + i * 256;
            int n = id >> 3, kq = (id & 7) * 4;
            *(float4*)&Bs[n][kq] = *(const float4*)(Bw + (size_t)(n0 + n) * 1024 + k0 + kq);
        }
        __syncthreads();
#pragma unroll
        for (int kk = 0; kk < 32; kk += 4) {
            float4 av[4], bv[8];
#pragma unroll
            for (int j = 0; j < 4; ++j) av[j] = *(float4*)&As[mi + j][kk];
#pragma unroll
            for (int j = 0; j < 8; ++j) bv[j] = *(float4*)&Bs[nj + j][kk];
#pragma unroll
            for (int j = 0; j < 4; ++j)
#pragma unroll
                for (int jj = 0; jj < 8; ++jj)
                    acc[j][jj] += av[j].x * bv[jj].x + av[j].y * bv[jj].y +
                                  av[j].z * bv[jj].z + av[j].w * bv[jj].w;
        }
    }

    if (MODE == 0) {
        int nbase = n0 + nj;
        int seg = nbase >> 10;
        int e = nbase & 1023;
        int hh = e >> 6, d = e & 63;
        u16* dst = (seg == 0) ? qb : (seg == 1) ? kb : vb;
        float bs[8];
#pragma unroll
        for (int jj = 0; jj < 8; ++jj) bs[jj] = bias[nbase + jj];
#pragma unroll
        for (int j = 0; j < 4; ++j) {
            int m = m0 + mi + j;
            int bb = m >> 10, s = m & 1023;
            size_t base = ((size_t)(bb * 16 + hh) * 1024 + s) * 64 + d;
            union { u16 u[8]; uint4 v; } pk;
#pragma unroll
            for (int jj = 0; jj < 8; ++jj) pk.u[jj] = f2bf(acc[j][jj] + bs[jj]);
            *(uint4*)(dst + base) = pk.v;
        }
    } else {
        float bs[8];
#pragma unroll
        for (int jj = 0; jj < 8; ++jj) bs[jj] = bias[n0 + nj + jj];
#pragma unroll
        for (int j = 0; j < 4; ++j) {
            int m = m0 + mi + j;
            float4 lo = make_float4(acc[j][0] + bs[0], acc[j][1] + bs[1],
                                    acc[j][2] + bs[2], acc[j][3] + bs[3]);
            float4 hi = make_float4(acc[j][4] + bs[4], acc[j][5] + bs[5],
                                    acc[j][6] + bs[6], acc[j][7] + bs[7]);
            *(float4*)(outf + (size_t)m * 1024 + n0 + nj) = lo;
            *(float4*)(outf + (size_t)m * 1024 + n0 + nj + 4) = hi;
        }
    }
}

// ---------------------------------------------------------------------------
// Fused attention: per block = (b, 16 q-rows), loop over 16 heads.
// scores -> softmax -> accumulate head-mean into aw (global, block-owned) ->
// PV -> o (bf16, [B,S,E] layout).
// ---------------------------------------------------------------------------
#define SCW 1032
__global__ __launch_bounds__(256) void attn_kernel(
    const u16* __restrict__ qg, const u16* __restrict__ kg,
    const u16* __restrict__ vg, float* __restrict__ aw, u16* __restrict__ og) {
    __shared__ float sc[16][SCW];
    __shared__ float kv[128][68];
    __shared__ float qt[16][68];
    __shared__ float red[16][17];
    __shared__ float rowv[16];
    const int t = threadIdx.x;
    const int q0 = blockIdx.x * 16;
    const int b = blockIdx.y;
    const float scale = 0.125f;  // 1/sqrt(64)
    const int rbase = (t >> 6) * 4;
    const int c0 = t & 63;
    const int r = t >> 4;
    const int c4 = (t & 15) * 4;
    const int dbase = (t & 15) * 4;

    for (int h = 0; h < H; ++h) {
        const size_t hb = (size_t)(b * H + h) * S * 64;
        // load Q tile 16x64 (bf16 -> f32)
        {
            int flat = t * 4;
            int rr = flat >> 6, d = flat & 63;
            ushort4 u = *(const ushort4*)(qg + hb + (size_t)(q0 + rr) * 64 + d);
            qt[rr][d] = bf2f(u.x); qt[rr][d + 1] = bf2f(u.y);
            qt[rr][d + 2] = bf2f(u.z); qt[rr][d + 3] = bf2f(u.w);
        }
        // scores: 8 K-tiles of 128 columns
        for (int kt0 = 0; kt0 < 8; ++kt0) {
            __syncthreads();
#pragma unroll
            for (int i = 0; i < 8; ++i) {
                int id = t + i * 256;
                int row = id >> 4, d = (id & 15) * 4;
                ushort4 u = *(const ushort4*)(kg + hb + (size_t)(kt0 * 128 + row) * 64 + d);
                kv[row][d] = bf2f(u.x); kv[row][d + 1] = bf2f(u.y);
                kv[row][d + 2] = bf2f(u.z); kv[row][d + 3] = bf2f(u.w);
            }
            __syncthreads();
            float a0[4], a1[4];
#pragma unroll
            for (int j = 0; j < 4; ++j) { a0[j] = 0.f; a1[j] = 0.f; }
#pragma unroll
            for (int d0 = 0; d0 < 64; d0 += 4) {
                float4 k0v = *(float4*)&kv[c0][d0];
                float4 k1v = *(float4*)&kv[c0 + 64][d0];
#pragma unroll
                for (int j = 0; j < 4; ++j) {
                    float4 qv = *(float4*)&qt[rbase + j][d0];
                    a0[j] += qv.x * k0v.x + qv.y * k0v.y + qv.z * k0v.z + qv.w * k0v.w;
                    a1[j] += qv.x * k1v.x + qv.y * k1v.y + qv.z * k1v.z + qv.w * k1v.w;
                }
            }
#pragma unroll
            for (int j = 0; j < 4; ++j) {
                sc[rbase + j][kt0 * 128 + c0] = a0[j] * scale;
                sc[rbase + j][kt0 * 128 + c0 + 64] = a1[j] * scale;
            }
        }
        __syncthreads();
        // softmax over row r (16 threads per row)
        {
            float m = -1e30f;
#pragma unroll
            for (int i = 0; i < 16; ++i) {
                float4 w = *(float4*)&sc[r][c4 + 64 * i];
                m = fmaxf(m, fmaxf(fmaxf(w.x, w.y), fmaxf(w.z, w.w)));
            }
            red[r][t & 15] = m;
            __syncthreads();
            if (t < 16) {
                float mm = red[t][0];
                for (int i = 1; i < 16; ++i) mm = fmaxf(mm, red[t][i]);
                rowv[t] = mm;
            }
            __syncthreads();
            float mrow = rowv[r];
            float ssum = 0.f;
#pragma unroll
            for (int i = 0; i < 16; ++i) {
                float4 w = *(float4*)&sc[r][c4 + 64 * i];
                w.x = __expf(w.x - mrow); w.y = __expf(w.y - mrow);
                w.z = __expf(w.z - mrow); w.w = __expf(w.w - mrow);
                *(float4*)&sc[r][c4 + 64 * i] = w;
                ssum += w.x + w.y + w.z + w.w;
            }
            __syncthreads();
            red[r][t & 15] = ssum;
            __syncthreads();
            if (t < 16) {
                float ss = 0.f;
                for (int i = 0; i < 16; ++i) ss += red[t][i];
                rowv[t] = 1.0f / ss;
            }
            __syncthreads();
            float inv = rowv[r];
            float* awrow = aw + (size_t)(b * S + q0 + r) * S;
#pragma unroll
            for (int i = 0; i < 16; ++i) {
                float4 w = *(float4*)&sc[r][c4 + 64 * i];
                w.x *= inv; w.y *= inv; w.z *= inv; w.w *= inv;
                *(float4*)&sc[r][c4 + 64 * i] = w;
                float4 a;
                if (h == 0) {
                    a = make_float4(w.x * 0.0625f, w.y * 0.0625f,
                                    w.z * 0.0625f, w.w * 0.0625f);
                } else {
                    a = *(float4*)(awrow + c4 + 64 * i);
                    a.x += w.x * 0.0625f; a.y += w.y * 0.0625f;
                    a.z += w.z * 0.0625f; a.w += w.w * 0.0625f;
                }
                *(float4*)(awrow + c4 + 64 * i) = a;
            }
        }
        // PV: o[r][dbase..dbase+3] accumulated over 8 V-tiles
        float4 oa = make_float4(0.f, 0.f, 0.f, 0.f);
        for (int kt0 = 0; kt0 < 8; ++kt0) {
            __syncthreads();
#pragma unroll
            for (int i = 0; i < 8; ++i) {
                int id = t + i * 256;
                int row = id >> 4, d = (id & 15) * 4;
                ushort4 u = *(const ushort4*)(vg + hb + (size_t)(kt0 * 128 + row) * 64 + d);
                kv[row][d] = bf2f(u.x); kv[row][d + 1] = bf2f(u.y);
                kv[row][d + 2] = bf2f(u.z); kv[row][d + 3] = bf2f(u.w);
            }
            __syncthreads();
#pragma unroll 8
            for (int k = 0; k < 128; k += 4) {
                float4 w4 = *(float4*)&sc[r][kt0 * 128 + k];
                float4 v0 = *(float4*)&kv[k][dbase];
                float4 v1 = *(float4*)&kv[k + 1][dbase];
                float4 v2 = *(float4*)&kv[k + 2][dbase];
                float4 v3 = *(float4*)&kv[k + 3][dbase];
                oa.x += w4.x * v0.x + w4.y * v1.x + w4.z * v2.x + w4.w * v3.x;
                oa.y += w4.x * v0.y + w4.y * v1.y + w4.z * v2.y + w4.w * v3.y;
                oa.z += w4.x * v0.z + w4.y * v1.z + w4.z * v2.z + w4.w * v3.z;
                oa.w += w4.x * v0.w + w4.y * v1.w + w4.z * v2.w + w4.w * v3.w;
            }
        }
        union { u16 u[4]; ushort4 v; } pk;
        pk.u[0] = f2bf(oa.x); pk.u[1] = f2bf(oa.y);
        pk.u[2] = f2bf(oa.z); pk.u[3] = f2bf(oa.w);
        *(ushort4*)(og + (size_t)(b * S + q0 + r) * E + h * 64 + dbase) = pk.v;
        __syncthreads();
    }
}

// ---------------------------------------------------------------------------
// Clustering stage A: per-row bitmask of (aw > 0.5) via ballot.
// grid (16, B), 256 threads = 4 waves, each wave owns 16 rows.
// ---------------------------------------------------------------------------
__global__ __launch_bounds__(256) void mask_kernel(const float* __restrict__ aw,
                                                   u64* __restrict__ maskg) {
    const int t = threadIdx.x;
    const int b = blockIdx.y;
    const int i0 = blockIdx.x * 64;
    const int wv = t >> 6, lane = t & 63;
    for (int rr = 0; rr < 16; ++rr) {
        int i = i0 + wv * 16 + rr;
        const float* row = aw + (size_t)(b * S + i) * S;
#pragma unroll
        for (int jj = 0; jj < 16; ++jj) {
            u64 bal = __ballot(row[lane + 64 * jj] > 0.5f);
            if (lane == 0) maskg[(size_t)(b * S + i) * 16 + jj] = bal;
        }
    }
}

// ---------------------------------------------------------------------------
// Clustering stage B: exactly-sequential greedy scan, one block per batch,
// masks in LDS, visited as one u64 register per lane (wave 0 only).
// ---------------------------------------------------------------------------
__global__ __launch_bounds__(256) void cluster_kernel(
    const u64* __restrict__ maskg, float* __restrict__ cid, u64* __restrict__ cov) {
    __shared__ u64 mask[16384];
    const int t = threadIdx.x;
    const int b = blockIdx.x;
#pragma unroll
    for (int i = 0; i < 64; ++i)
        mask[t + 256 * i] = maskg[(size_t)b * 16384 + t + 256 * i];
#pragma unroll
    for (int i = 0; i < 4; ++i) cid[b * S + t + 256 * i] = -1.0f;
    __syncthreads();
    if (t < 64) {
        u64 vis = 0;
        const int w = t;
        for (int i = 0; i < 1024; ++i) {
            u64 viw = __shfl(vis, i >> 6);
            bool proc = ((viw >> (i & 63)) & 1ULL) == 0ULL;
            u64 cl = (proc && w < 16) ? mask[i * 16 + w] : 0ULL;
            u64 newly = cl & ~vis;
            vis |= cl;
            while (newly) {
                int bit = __ffsll((long long)newly) - 1;
                cid[b * S + w * 64 + bit] = (float)i;
                newly &= newly - 1;
            }
        }
        if (t < 16) cov[b * 16 + t] = vis;
    }
}

// ---------------------------------------------------------------------------
// clustered_outputs = covered ? x : -1e9
// ---------------------------------------------------------------------------
__global__ __launch_bounds__(256) void clustered_kernel(
    const float* __restrict__ x, const u64* __restrict__ cov,
    float* __restrict__ out2) {
    const size_t n4 = (size_t)B * S * E / 4;
    size_t idx = (size_t)blockIdx.x * 256 + threadIdx.x;
    const float4 neg = make_float4(-1e9f, -1e9f, -1e9f, -1e9f);
    for (; idx < n4; idx += (size_t)gridDim.x * 256) {
        size_t tok = idx >> 8;
        int bb = (int)(tok >> 10), s = (int)(tok & 1023);
        u64 m = cov[bb * 16 + (s >> 6)];
        bool c = ((m >> (s & 63)) & 1ULL) != 0ULL;
        float4 v = ((const float4*)x)[idx];
        ((float4*)out2)[idx] = c ? v : neg;
    }
}

extern "C" void kernel_launch(void* const* d_in, const int* in_sizes, int n_in,
                              void* d_out, int out_size, void* d_ws, size_t ws_size,
                              hipStream_t stream) {
    const float* x = (const float*)d_in[0];
    const float* w_in = (const float*)d_in[1];
    const float* b_in = (const float*)d_in[2];
    const float* w_out = (const float*)d_in[3];
    const float* b_out = (const float*)d_in[4];

    float* out0 = (float*)d_out;            // attn_output  [8,1024,1024]
    float* out1 = out0 + 8388608;           // attn_weights [8,1024,1024]
    float* out2 = out1 + 8388608;           // clustered    [8,1024,1024]
    float* out3 = out2 + 8388608;           // cluster_ids  [8,1024] (as float)

    // bf16 staging: q in attn_output region (dead before out-proj writes it),
    // k/v in clustered region (dead before final masked copy).
    u16* q_bf = (u16*)out0;
    u16* k_bf = (u16*)out2;
    u16* v_bf = k_bf + 8388608;
    // workspace: o (16 MB) + row masks (1 MB) + covered bits (1 KB)
    u16* o_bf = (u16*)d_ws;
    u64* maskg = (u64*)((char*)d_ws + (size_t)(16u << 20));
    u64* cov = (u64*)((char*)d_ws + (size_t)(17u << 20));

    gemm_kernel<0><<<dim3(128, 24), 256, 0, stream>>>(
        x, nullptr, w_in, b_in, nullptr, q_bf, k_bf, v_bf);
    attn_kernel<<<dim3(64, 8), 256, 0, stream>>>(q_bf, k_bf, v_bf, out1, o_bf);
    gemm_kernel<1><<<dim3(128, 8), 256, 0, stream>>>(
        nullptr, o_bf, w_out, b_out, out0, nullptr, nullptr, nullptr);
    mask_kernel<<<dim3(16, 8), 256, 0, stream>>>(out1, maskg);
    cluster_kernel<<<8, 256, 0, stream>>>(maskg, out3, cov);
    clustered_kernel<<<2048, 256, 0, stream>>>(x, cov, out2);
}

// Round 2
// 563.742 us; speedup vs baseline: 8.2920x; 8.2920x over previous
//
#include <hip/hip_runtime.h>
#include <hip/hip_bf16.h>

#define B 8
#define S 1024
#define E 1024
#define H 16

typedef unsigned short u16;
typedef unsigned int u32;
typedef unsigned long long u64;

typedef __attribute__((ext_vector_type(8))) short s16x8;
typedef __attribute__((ext_vector_type(4))) float f32x4;

__device__ __forceinline__ float bf2f(u16 u) {
    union { u32 i; float f; } x; x.i = ((u32)u) << 16; return x.f;
}
__device__ __forceinline__ u16 f2bf(float f) {
    union { float f; u32 i; } x; x.f = f;
    u32 r = x.i + 0x7FFFu + ((x.i >> 16) & 1u);
    return (u16)(r >> 16);
}

// ---------------------------------------------------------------------------
// fp32 -> bf16 conversion (x, W_in, W_out)
// ---------------------------------------------------------------------------
__global__ __launch_bounds__(256) void cvt_kernel(const float* __restrict__ in,
                                                  u16* __restrict__ out, int n4) {
    int i = blockIdx.x * 256 + threadIdx.x;
    if (i < n4) {
        float4 v = ((const float4*)in)[i];
        union { u16 u[4]; ushort4 s; } p;
        p.u[0] = f2bf(v.x); p.u[1] = f2bf(v.y);
        p.u[2] = f2bf(v.z); p.u[3] = f2bf(v.w);
        ((ushort4*)out)[i] = p.s;
    }
}

// ---------------------------------------------------------------------------
// MFMA GEMM: C[m,n] = sum_k A[m,k]*W[n,k] + bias[n].  A,W bf16 row-major(K).
// 128x128 tile, BK=64, 256 thr (4 waves, 2x2 quadrants of 64x64, 4x4 frags).
// MODE 0 (qkv): n<1024 -> q [B,H,S,64]; n<2048 -> k [B,H,S,64];
//               n>=2048 -> vt [B,H,64,S] (transposed V, packed 4-wide stores).
// MODE 1: C fp32 -> outf [M][1024].
// ---------------------------------------------------------------------------
template <int MODE>
__global__ __launch_bounds__(256) void mfma_gemm(
    const u16* __restrict__ A, const u16* __restrict__ W,
    const float* __restrict__ bias, u16* __restrict__ qb, u16* __restrict__ kb,
    u16* __restrict__ vt, float* __restrict__ outf) {
    __shared__ u16 As[128 * 72];   // row stride 72 elems = 144B (aligned, 2-way banks)
    __shared__ u16 Bs[128 * 72];
    const int t = threadIdx.x;
    const int lane = t & 63;
    const int w = t >> 6;
    const int m0 = blockIdx.x * 128;
    const int n0 = blockIdx.y * 128;
    const int wm = w >> 1, wn = w & 1;
    const int l15 = lane & 15, l4 = lane >> 4;

    f32x4 acc[4][4];
#pragma unroll
    for (int i = 0; i < 4; ++i)
#pragma unroll
        for (int j = 0; j < 4; ++j) acc[i][j] = {0.f, 0.f, 0.f, 0.f};

    for (int k0 = 0; k0 < 1024; k0 += 64) {
        __syncthreads();
#pragma unroll
        for (int i = 0; i < 4; ++i) {
            int slot = i * 256 + t;
            int row = slot >> 3, seg = slot & 7;
            s16x8 va = *(const s16x8*)(A + (size_t)(m0 + row) * 1024 + k0 + seg * 8);
            s16x8 vb = *(const s16x8*)(W + (size_t)(n0 + row) * 1024 + k0 + seg * 8);
            *(s16x8*)(As + row * 72 + seg * 8) = va;
            *(s16x8*)(Bs + row * 72 + seg * 8) = vb;
        }
        __syncthreads();
#pragma unroll
        for (int ks = 0; ks < 2; ++ks) {
            s16x8 af[4], bf[4];
#pragma unroll
            for (int i = 0; i < 4; ++i)
                af[i] = *(const s16x8*)(As + (wm * 64 + i * 16 + l15) * 72 + ks * 32 + l4 * 8);
#pragma unroll
            for (int j = 0; j < 4; ++j)
                bf[j] = *(const s16x8*)(Bs + (wn * 64 + j * 16 + l15) * 72 + ks * 32 + l4 * 8);
#pragma unroll
            for (int i = 0; i < 4; ++i)
#pragma unroll
                for (int j = 0; j < 4; ++j)
                    acc[i][j] = __builtin_amdgcn_mfma_f32_16x16x32_bf16(
                        af[i], bf[j], acc[i][j], 0, 0, 0);
        }
    }

    if (MODE == 0) {
#pragma unroll
        for (int j = 0; j < 4; ++j) {
            int n = n0 + wn * 64 + j * 16 + l15;
            float bn = bias[n];
            int seg = n >> 10;
            int e = n & 1023;
            int hh = e >> 6, d = e & 63;
#pragma unroll
            for (int i = 0; i < 4; ++i) {
                int mbase = m0 + wm * 64 + i * 16 + l4 * 4;
                int bb = mbase >> 10, sb = mbase & 1023;
                if (seg == 2) {
                    union { u16 u[4]; ushort4 s; } p;
#pragma unroll
                    for (int rr = 0; rr < 4; ++rr) p.u[rr] = f2bf(acc[i][j][rr] + bn);
                    *(ushort4*)(vt + ((size_t)(bb * 16 + hh) * 64 + d) * 1024 + sb) = p.s;
                } else {
                    u16* dst = (seg == 0) ? qb : kb;
#pragma unroll
                    for (int rr = 0; rr < 4; ++rr)
                        dst[((size_t)(bb * 16 + hh) * 1024 + sb + rr) * 64 + d] =
                            f2bf(acc[i][j][rr] + bn);
                }
            }
        }
    } else {
#pragma unroll
        for (int j = 0; j < 4; ++j) {
            int n = n0 + wn * 64 + j * 16 + l15;
            float bn = bias[n];
#pragma unroll
            for (int i = 0; i < 4; ++i) {
                int mbase = m0 + wm * 64 + i * 16 + l4 * 4;
#pragma unroll
                for (int rr = 0; rr < 4; ++rr)
                    outf[(size_t)(mbase + rr) * 1024 + n] = acc[i][j][rr] + bn;
            }
        }
    }
}

// ---------------------------------------------------------------------------
// MFMA attention. Block = (32 q-rows, batch b), 512 thr (8 waves), loop heads.
// QK^T: wave w owns cols [w*128,w*128+128), frags direct from global.
// Scores bf16 in LDS (stride 1032). Wave-parallel softmax (16 thr/row).
// aw head-mean accumulated in registers, written once at the end.
// PV: wave (mw=w>>2, dw=w&3) -> O rows mw*16+, cols d dw*16+; A=P from LDS,
// B=V^T rows direct from global (contiguous along contracted dim).
// ---------------------------------------------------------------------------
__global__ __launch_bounds__(512, 2) void attn_mfma(
    const u16* __restrict__ q, const u16* __restrict__ k,
    const u16* __restrict__ vt, float* __restrict__ aw, u16* __restrict__ o) {
    __shared__ u16 sc[32 * 1032];
    const int t = threadIdx.x;
    const int lane = t & 63;
    const int w = t >> 6;
    const int l15 = lane & 15, l4 = lane >> 4;
    const int q0 = blockIdx.x * 32;
    const int b = blockIdx.y;
    const int mw = w >> 2, dw = w & 3;
    const int r = t >> 4, c16 = t & 15;

    f32x4 awacc[16];
#pragma unroll
    for (int i = 0; i < 16; ++i) awacc[i] = {0.f, 0.f, 0.f, 0.f};

    for (int h = 0; h < 16; ++h) {
        const size_t hb = (size_t)(b * 16 + h) << 16;  // *S*64 = *65536
        // ---- QK^T ----
        s16x8 qa[2][2];
#pragma unroll
        for (int mi = 0; mi < 2; ++mi)
#pragma unroll
            for (int ks = 0; ks < 2; ++ks)
                qa[mi][ks] = *(const s16x8*)(q + hb + (size_t)(q0 + mi * 16 + l15) * 64 +
                                             ks * 32 + l4 * 8);
        f32x4 acc[2][8];
#pragma unroll
        for (int mi = 0; mi < 2; ++mi)
#pragma unroll
            for (int ji = 0; ji < 8; ++ji) acc[mi][ji] = {0.f, 0.f, 0.f, 0.f};
#pragma unroll
        for (int ji = 0; ji < 8; ++ji) {
            const u16* kp = k + hb + (size_t)(w * 128 + ji * 16 + l15) * 64 + l4 * 8;
            s16x8 kb0 = *(const s16x8*)(kp);
            s16x8 kb1 = *(const s16x8*)(kp + 32);
            acc[0][ji] = __builtin_amdgcn_mfma_f32_16x16x32_bf16(qa[0][0], kb0, acc[0][ji], 0, 0, 0);
            acc[1][ji] = __builtin_amdgcn_mfma_f32_16x16x32_bf16(qa[1][0], kb0, acc[1][ji], 0, 0, 0);
            acc[0][ji] = __builtin_amdgcn_mfma_f32_16x16x32_bf16(qa[0][1], kb1, acc[0][ji], 0, 0, 0);
            acc[1][ji] = __builtin_amdgcn_mfma_f32_16x16x32_bf16(qa[1][1], kb1, acc[1][ji], 0, 0, 0);
        }
#pragma unroll
        for (int mi = 0; mi < 2; ++mi)
#pragma unroll
            for (int ji = 0; ji < 8; ++ji) {
                int m = mi * 16 + l4 * 4;
                int jj = w * 128 + ji * 16 + l15;
#pragma unroll
                for (int rr = 0; rr < 4; ++rr)
                    sc[(m + rr) * 1032 + jj] = f2bf(acc[mi][ji][rr] * 0.125f);
            }
        __syncthreads();
        // ---- softmax on row r (16 threads/row), cols c16*4 + 64*i ----
        {
            float p[64];
            float mx = -1e30f;
#pragma unroll
            for (int i = 0; i < 16; ++i) {
                ushort4 u = *(const ushort4*)(sc + r * 1032 + c16 * 4 + 64 * i);
                p[4 * i + 0] = bf2f(u.x); p[4 * i + 1] = bf2f(u.y);
                p[4 * i + 2] = bf2f(u.z); p[4 * i + 3] = bf2f(u.w);
                mx = fmaxf(mx, fmaxf(fmaxf(p[4 * i], p[4 * i + 1]),
                                     fmaxf(p[4 * i + 2], p[4 * i + 3])));
            }
#pragma unroll
            for (int s = 1; s < 16; s <<= 1) mx = fmaxf(mx, __shfl_xor(mx, s));
            float sum = 0.f;
#pragma unroll
            for (int i = 0; i < 64; ++i) { p[i] = __expf(p[i] - mx); sum += p[i]; }
#pragma unroll
            for (int s = 1; s < 16; s <<= 1) sum += __shfl_xor(sum, s);
            float inv = 1.0f / sum;
#pragma unroll
            for (int i = 0; i < 16; ++i) {
                float w0 = p[4 * i + 0] * inv, w1 = p[4 * i + 1] * inv;
                float w2 = p[4 * i + 2] * inv, w3 = p[4 * i + 3] * inv;
                union { u16 u[4]; ushort4 s; } pk;
                pk.u[0] = f2bf(w0); pk.u[1] = f2bf(w1);
                pk.u[2] = f2bf(w2); pk.u[3] = f2bf(w3);
                *(ushort4*)(sc + r * 1032 + c16 * 4 + 64 * i) = pk.s;
                awacc[i][0] += w0 * 0.0625f; awacc[i][1] += w1 * 0.0625f;
                awacc[i][2] += w2 * 0.0625f; awacc[i][3] += w3 * 0.0625f;
            }
        }
        __syncthreads();
        // ---- PV ----
        f32x4 oacc[4];
#pragma unroll
        for (int i = 0; i < 4; ++i) oacc[i] = {0.f, 0.f, 0.f, 0.f};
#pragma unroll 8
        for (int ks = 0; ks < 32; ++ks) {
            s16x8 pa = *(const s16x8*)(sc + (mw * 16 + l15) * 1032 + ks * 32 + l4 * 8);
            s16x8 vb = *(const s16x8*)(vt + hb + (size_t)(dw * 16 + l15) * 1024 +
                                       ks * 32 + l4 * 8);
            oacc[ks & 3] = __builtin_amdgcn_mfma_f32_16x16x32_bf16(pa, vb, oacc[ks & 3], 0, 0, 0);
        }
        f32x4 of = oacc[0] + oacc[1] + oacc[2] + oacc[3];
#pragma unroll
        for (int rr = 0; rr < 4; ++rr)
            o[(size_t)(b * 1024 + q0 + mw * 16 + l4 * 4 + rr) * 1024 + h * 64 +
              dw * 16 + l15] = f2bf(of[rr]);
        __syncthreads();
    }
    // ---- write head-averaged attn weights ----
    float* awrow = aw + (size_t)(b * 1024 + q0 + r) * 1024;
#pragma unroll
    for (int i = 0; i < 16; ++i)
        *(f32x4*)(awrow + c16 * 4 + 64 * i) = awacc[i];
}

// ---------------------------------------------------------------------------
// Clustering stage A: per-row bitmask of (aw > 0.5) via ballot.
// ---------------------------------------------------------------------------
__global__ __launch_bounds__(256) void mask_kernel(const float* __restrict__ aw,
                                                   u64* __restrict__ maskg) {
    const int t = threadIdx.x;
    const int b = blockIdx.y;
    const int i0 = blockIdx.x * 64;
    const int wv = t >> 6, lane = t & 63;
    for (int rr = 0; rr < 16; ++rr) {
        int i = i0 + wv * 16 + rr;
        const float* row = aw + (size_t)(b * S + i) * S;
#pragma unroll
        for (int jj = 0; jj < 16; ++jj) {
            u64 bal = __ballot(row[lane + 64 * jj] > 0.5f);
            if (lane == 0) maskg[(size_t)(b * S + i) * 16 + jj] = bal;
        }
    }
}

// ---------------------------------------------------------------------------
// Clustering stage B: exactly-sequential greedy scan.
// ---------------------------------------------------------------------------
__global__ __launch_bounds__(256) void cluster_kernel(
    const u64* __restrict__ maskg, float* __restrict__ cid, u64* __restrict__ cov) {
    __shared__ u64 mask[16384];
    const int t = threadIdx.x;
    const int b = blockIdx.x;
#pragma unroll
    for (int i = 0; i < 64; ++i)
        mask[t + 256 * i] = maskg[(size_t)b * 16384 + t + 256 * i];
#pragma unroll
    for (int i = 0; i < 4; ++i) cid[b * S + t + 256 * i] = -1.0f;
    __syncthreads();
    if (t < 64) {
        u64 vis = 0;
        const int w = t;
        for (int i = 0; i < 1024; ++i) {
            u64 viw = __shfl(vis, i >> 6);
            bool proc = ((viw >> (i & 63)) & 1ULL) == 0ULL;
            u64 cl = (proc && w < 16) ? mask[i * 16 + w] : 0ULL;
            u64 newly = cl & ~vis;
            vis |= cl;
            while (newly) {
                int bit = __ffsll((long long)newly) - 1;
                cid[b * S + w * 64 + bit] = (float)i;
                newly &= newly - 1;
            }
        }
        if (t < 16) cov[b * 16 + t] = vis;
    }
}

// ---------------------------------------------------------------------------
// clustered_outputs = covered ? x : -1e9
// ---------------------------------------------------------------------------
__global__ __launch_bounds__(256) void clustered_kernel(
    const float* __restrict__ x, const u64* __restrict__ cov,
    float* __restrict__ out2) {
    const size_t n4 = (size_t)B * S * E / 4;
    size_t idx = (size_t)blockIdx.x * 256 + threadIdx.x;
    const float4 neg = make_float4(-1e9f, -1e9f, -1e9f, -1e9f);
    for (; idx < n4; idx += (size_t)gridDim.x * 256) {
        size_t tok = idx >> 8;
        int bb = (int)(tok >> 10), s = (int)(tok & 1023);
        u64 m = cov[bb * 16 + (s >> 6)];
        bool c = ((m >> (s & 63)) & 1ULL) != 0ULL;
        float4 v = ((const float4*)x)[idx];
        ((float4*)out2)[idx] = c ? v : neg;
    }
}

extern "C" void kernel_launch(void* const* d_in, const int* in_sizes, int n_in,
                              void* d_out, int out_size, void* d_ws, size_t ws_size,
                              hipStream_t stream) {
    const float* x = (const float*)d_in[0];
    const float* w_in = (const float*)d_in[1];
    const float* b_in = (const float*)d_in[2];
    const float* w_out = (const float*)d_in[3];
    const float* b_out = (const float*)d_in[4];

    float* out0 = (float*)d_out;        // attn_output  [8,1024,1024]
    float* out1 = out0 + 8388608;       // attn_weights [8,1024,1024]
    float* out2 = out1 + 8388608;       // clustered    [8,1024,1024]
    float* out3 = out2 + 8388608;       // cluster_ids  [8,1024] (as float)

    // bf16 staging (all regions dead before their final output is written):
    u16* q_bf = (u16*)out0;             // [B,H,S,64]
    u16* vt_bf = q_bf + 8388608;        // [B,H,64,S]  (transposed V)
    u16* xb = (u16*)out1;               // x as bf16
    u16* k_bf = (u16*)out2;             // [B,H,S,64]
    u16* wb0 = k_bf + 8388608;          // W_in bf16 [3072][1024]
    u16* wb1 = wb0 + 3145728;           // W_out bf16 [1024][1024]
    u16* o_bf = (u16*)d_ws;             // attention output bf16 [B,S,E]
    u64* maskg = (u64*)((char*)d_ws + (size_t)(16u << 20));
    u64* cov = (u64*)((char*)d_ws + (size_t)(17u << 20));

    cvt_kernel<<<8192, 256, 0, stream>>>(x, xb, 2097152);
    cvt_kernel<<<3072, 256, 0, stream>>>(w_in, wb0, 786432);
    cvt_kernel<<<1024, 256, 0, stream>>>(w_out, wb1, 262144);

    mfma_gemm<0><<<dim3(64, 24), 256, 0, stream>>>(xb, wb0, b_in, q_bf, k_bf,
                                                   vt_bf, nullptr);
    attn_mfma<<<dim3(32, 8), 512, 0, stream>>>(q_bf, k_bf, vt_bf, out1, o_bf);
    mfma_gemm<1><<<dim3(64, 8), 256, 0, stream>>>(o_bf, wb1, b_out, nullptr,
                                                  nullptr, nullptr, out0);

    mask_kernel<<<dim3(16, 8), 256, 0, stream>>>(out1, maskg);
    cluster_kernel<<<8, 256, 0, stream>>>(maskg, out3, cov);
    clustered_kernel<<<2048, 256, 0, stream>>>(x, cov, out2);
}

// Round 3
// 422.000 us; speedup vs baseline: 11.0771x; 1.3359x over previous
//
#include <hip/hip_runtime.h>
#include <hip/hip_bf16.h>

#define B 8
#define S 1024
#define E 1024
#define H 16

typedef unsigned short u16;
typedef unsigned int u32;
typedef unsigned long long u64;

typedef __attribute__((ext_vector_type(8))) short s16x8;
typedef __attribute__((ext_vector_type(4))) float f32x4;
typedef __attribute__((ext_vector_type(16))) float f32x16;

__device__ __forceinline__ float bf2f(u16 u) {
    union { u32 i; float f; } x; x.i = ((u32)u) << 16; return x.f;
}
__device__ __forceinline__ u16 f2bf(float f) {
    union { float f; u32 i; } x; x.f = f;
    u32 r = x.i + 0x7FFFu + ((x.i >> 16) & 1u);
    return (u16)(r >> 16);
}
__device__ __forceinline__ f32x16 zero16() {
    f32x16 z;
#pragma unroll
    for (int i = 0; i < 16; ++i) z[i] = 0.f;
    return z;
}

// ---------------------------------------------------------------------------
// fp32 -> bf16 conversion (x, W_in, W_out)
// ---------------------------------------------------------------------------
__global__ __launch_bounds__(256) void cvt_kernel(const float* __restrict__ in,
                                                  u16* __restrict__ out, int n4) {
    int i = blockIdx.x * 256 + threadIdx.x;
    if (i < n4) {
        float4 v = ((const float4*)in)[i];
        union { u16 u[4]; ushort4 s; } p;
        p.u[0] = f2bf(v.x); p.u[1] = f2bf(v.y);
        p.u[2] = f2bf(v.z); p.u[3] = f2bf(v.w);
        ((ushort4*)out)[i] = p.s;
    }
}

// ---------------------------------------------------------------------------
// MFMA GEMM (unchanged from round 2 — correct, to be tuned next round).
// ---------------------------------------------------------------------------
template <int MODE>
__global__ __launch_bounds__(256) void mfma_gemm(
    const u16* __restrict__ A, const u16* __restrict__ W,
    const float* __restrict__ bias, u16* __restrict__ qb, u16* __restrict__ kb,
    u16* __restrict__ vt, float* __restrict__ outf) {
    __shared__ u16 As[128 * 72];
    __shared__ u16 Bs[128 * 72];
    const int t = threadIdx.x;
    const int lane = t & 63;
    const int w = t >> 6;
    const int m0 = blockIdx.x * 128;
    const int n0 = blockIdx.y * 128;
    const int wm = w >> 1, wn = w & 1;
    const int l15 = lane & 15, l4 = lane >> 4;

    f32x4 acc[4][4];
#pragma unroll
    for (int i = 0; i < 4; ++i)
#pragma unroll
        for (int j = 0; j < 4; ++j) acc[i][j] = {0.f, 0.f, 0.f, 0.f};

    for (int k0 = 0; k0 < 1024; k0 += 64) {
        __syncthreads();
#pragma unroll
        for (int i = 0; i < 4; ++i) {
            int slot = i * 256 + t;
            int row = slot >> 3, seg = slot & 7;
            s16x8 va = *(const s16x8*)(A + (size_t)(m0 + row) * 1024 + k0 + seg * 8);
            s16x8 vb = *(const s16x8*)(W + (size_t)(n0 + row) * 1024 + k0 + seg * 8);
            *(s16x8*)(As + row * 72 + seg * 8) = va;
            *(s16x8*)(Bs + row * 72 + seg * 8) = vb;
        }
        __syncthreads();
#pragma unroll
        for (int ks = 0; ks < 2; ++ks) {
            s16x8 af[4], bf[4];
#pragma unroll
            for (int i = 0; i < 4; ++i)
                af[i] = *(const s16x8*)(As + (wm * 64 + i * 16 + l15) * 72 + ks * 32 + l4 * 8);
#pragma unroll
            for (int j = 0; j < 4; ++j)
                bf[j] = *(const s16x8*)(Bs + (wn * 64 + j * 16 + l15) * 72 + ks * 32 + l4 * 8);
#pragma unroll
            for (int i = 0; i < 4; ++i)
#pragma unroll
                for (int j = 0; j < 4; ++j)
                    acc[i][j] = __builtin_amdgcn_mfma_f32_16x16x32_bf16(
                        af[i], bf[j], acc[i][j], 0, 0, 0);
        }
    }

    if (MODE == 0) {
#pragma unroll
        for (int j = 0; j < 4; ++j) {
            int n = n0 + wn * 64 + j * 16 + l15;
            float bn = bias[n];
            int seg = n >> 10;
            int e = n & 1023;
            int hh = e >> 6, d = e & 63;
#pragma unroll
            for (int i = 0; i < 4; ++i) {
                int mbase = m0 + wm * 64 + i * 16 + l4 * 4;
                int bb = mbase >> 10, sb = mbase & 1023;
                if (seg == 2) {
                    union { u16 u[4]; ushort4 s; } p;
#pragma unroll
                    for (int rr = 0; rr < 4; ++rr) p.u[rr] = f2bf(acc[i][j][rr] + bn);
                    *(ushort4*)(vt + ((size_t)(bb * 16 + hh) * 64 + d) * 1024 + sb) = p.s;
                } else {
                    u16* dst = (seg == 0) ? qb : kb;
#pragma unroll
                    for (int rr = 0; rr < 4; ++rr)
                        dst[((size_t)(bb * 16 + hh) * 1024 + sb + rr) * 64 + d] =
                            f2bf(acc[i][j][rr] + bn);
                }
            }
        }
    } else {
#pragma unroll
        for (int j = 0; j < 4; ++j) {
            int n = n0 + wn * 64 + j * 16 + l15;
            float bn = bias[n];
#pragma unroll
            for (int i = 0; i < 4; ++i) {
                int mbase = m0 + wm * 64 + i * 16 + l4 * 4;
#pragma unroll
                for (int rr = 0; rr < 4; ++rr)
                    outf[(size_t)(mbase + rr) * 1024 + n] = acc[i][j][rr] + bn;
            }
        }
    }
}

// ---------------------------------------------------------------------------
// build PV A-fragment from 8 exp-values (T12: cvt_pk + permlane32_swap).
// A-frag (32x32x16): lane holds P[q=lane&31][k16 = hi*8 + j].
// e[BASE..BASE+7] hold P at k_local = (r&3)+8*(r>>2)+4*hi for r=BASE..BASE+7.
// ---------------------------------------------------------------------------
template <int BASE>
__device__ __forceinline__ s16x8 build_pa(f32x16 e) {
    u32 a, bv, c, d;
    asm("v_cvt_pk_bf16_f32 %0, %1, %2" : "=v"(a) : "v"(e[BASE + 0]), "v"(e[BASE + 1]));
    asm("v_cvt_pk_bf16_f32 %0, %1, %2" : "=v"(bv) : "v"(e[BASE + 2]), "v"(e[BASE + 3]));
    asm("v_cvt_pk_bf16_f32 %0, %1, %2" : "=v"(c) : "v"(e[BASE + 4]), "v"(e[BASE + 5]));
    asm("v_cvt_pk_bf16_f32 %0, %1, %2" : "=v"(d) : "v"(e[BASE + 6]), "v"(e[BASE + 7]));
    asm("v_permlane32_swap_b32 %0, %1" : "+v"(a), "+v"(c));
    asm("v_permlane32_swap_b32 %0, %1" : "+v"(bv), "+v"(d));
    union { u32 w[4]; s16x8 v; } u;
    u.w[0] = a; u.w[1] = bv; u.w[2] = c; u.w[3] = d;
    return u.v;
}

// ---------------------------------------------------------------------------
// Attention, swapped-QK in-register softmax.
// Block = (32 q-rows, b), 1024 thr = 16 waves; wave w owns k-cols [w*64,w*64+64).
// Per head: QK^T (mfma(K,Q)) -> lane owns its q-row's 32 slice-scores in regs
// -> slice stats (in-lane + permlane) -> 1 LDS exchange -> exact softmax
// -> awacc (registers, persists across heads) -> PV via in-register P frags
// -> cross-wave O reduce via LDS slab.
// ---------------------------------------------------------------------------
__global__ __launch_bounds__(1024) void attn_mfma(
    const u16* __restrict__ qg, const u16* __restrict__ kg,
    const u16* __restrict__ vtg, float* __restrict__ aw, u16* __restrict__ og) {
    __shared__ float slab[8][32][66];   // [wave_pair][q][d + pad]
    __shared__ float stM[16][32];
    __shared__ float stL[16][32];
    const int t = threadIdx.x;
    const int lane = t & 63;
    const int w = t >> 6;            // 0..15
    const int q = lane & 31;
    const int hi = lane >> 5;
    const int q0 = blockIdx.x * 32;
    const int b = blockIdx.y;
    const int kslice = w * 64;

    f32x16 awA = zero16(), awB = zero16();

    for (int h = 0; h < 16; ++h) {
        const size_t hb = (size_t)(b * 16 + h) << 16;   // * S * 64
        // ---- Q B-fragments (lane holds Q[q0+q][d]) ----
        s16x8 qf[4];
#pragma unroll
        for (int s = 0; s < 4; ++s)
            qf[s] = *(const s16x8*)(qg + hb + (size_t)(q0 + q) * 64 + s * 16 + hi * 8);
        // ---- QK^T: two 32-k tiles; C[k][q], lane owns col q ----
        f32x16 sA, sB;
        {
            s16x8 ka[4];
#pragma unroll
            for (int s = 0; s < 4; ++s)
                ka[s] = *(const s16x8*)(kg + hb + (size_t)(kslice + q) * 64 + s * 16 + hi * 8);
            f32x16 c = zero16();
#pragma unroll
            for (int s = 0; s < 4; ++s)
                c = __builtin_amdgcn_mfma_f32_32x32x16_bf16(ka[s], qf[s], c, 0, 0, 0);
            sA = c * 0.125f;
        }
        {
            s16x8 ka[4];
#pragma unroll
            for (int s = 0; s < 4; ++s)
                ka[s] = *(const s16x8*)(kg + hb + (size_t)(kslice + 32 + q) * 64 + s * 16 + hi * 8);
            f32x16 c = zero16();
#pragma unroll
            for (int s = 0; s < 4; ++s)
                c = __builtin_amdgcn_mfma_f32_32x32x16_bf16(ka[s], qf[s], c, 0, 0, 0);
            sB = c * 0.125f;
        }
        // ---- slice max (in-lane tree + pair combine with lane^32) ----
        float m0 = -1e30f, m1 = -1e30f, m2 = -1e30f, m3 = -1e30f;
#pragma unroll
        for (int i = 0; i < 16; i += 4) {
            m0 = fmaxf(m0, fmaxf(sA[i + 0], sB[i + 0]));
            m1 = fmaxf(m1, fmaxf(sA[i + 1], sB[i + 1]));
            m2 = fmaxf(m2, fmaxf(sA[i + 2], sB[i + 2]));
            m3 = fmaxf(m3, fmaxf(sA[i + 3], sB[i + 3]));
        }
        float mw = fmaxf(fmaxf(m0, m1), fmaxf(m2, m3));
        {
            float a_ = mw, b_ = mw;
            asm("v_permlane32_swap_b32 %0, %1" : "+v"(a_), "+v"(b_));
            mw = fmaxf(a_, b_);
        }
        // ---- exp (slice-local) + slice sum ----
        float s0 = 0.f, s1 = 0.f, s2 = 0.f, s3 = 0.f;
#pragma unroll
        for (int i = 0; i < 16; i += 4) {
            sA[i + 0] = __expf(sA[i + 0] - mw); sB[i + 0] = __expf(sB[i + 0] - mw);
            sA[i + 1] = __expf(sA[i + 1] - mw); sB[i + 1] = __expf(sB[i + 1] - mw);
            sA[i + 2] = __expf(sA[i + 2] - mw); sB[i + 2] = __expf(sB[i + 2] - mw);
            sA[i + 3] = __expf(sA[i + 3] - mw); sB[i + 3] = __expf(sB[i + 3] - mw);
            s0 += sA[i + 0] + sB[i + 0]; s1 += sA[i + 1] + sB[i + 1];
            s2 += sA[i + 2] + sB[i + 2]; s3 += sA[i + 3] + sB[i + 3];
        }
        float lw = (s0 + s1) + (s2 + s3);
        {
            float a_ = lw, b_ = lw;
            asm("v_permlane32_swap_b32 %0, %1" : "+v"(a_), "+v"(b_));
            lw = a_ + b_;
        }
        if (hi == 0) { stM[w][q] = mw; stL[w][q] = lw; }
        __syncthreads();                      // SYNC_A
        // ---- combine stats across 16 waves ----
        float m = -1e30f;
#pragma unroll
        for (int i = 0; i < 16; ++i) m = fmaxf(m, stM[i][q]);
        float L = 0.f;
#pragma unroll
        for (int i = 0; i < 16; ++i) L += stL[i][q] * __expf(stM[i][q] - m);
        float inv = 1.0f / L;
        float scown = __expf(mw - m) * inv;   // rescale for this wave's slice
        float fac = scown * 0.0625f;          // /16 heads
        awA += sA * fac;
        awB += sB * fac;
        // ---- PV: P frags in-register, V^T B-frags from global ----
        s16x8 paA0 = build_pa<0>(sA), paA1 = build_pa<8>(sA);
        s16x8 paB0 = build_pa<0>(sB), paB1 = build_pa<8>(sB);
        f32x16 oLo = zero16(), oHi = zero16();
        {
            const u16* vbase = vtg + hb + kslice + hi * 8;
            s16x8 v0 = *(const s16x8*)(vbase + (size_t)q * 1024);
            s16x8 v1 = *(const s16x8*)(vbase + (size_t)(q + 32) * 1024);
            oLo = __builtin_amdgcn_mfma_f32_32x32x16_bf16(paA0, v0, oLo, 0, 0, 0);
            oHi = __builtin_amdgcn_mfma_f32_32x32x16_bf16(paA0, v1, oHi, 0, 0, 0);
            v0 = *(const s16x8*)(vbase + 16 + (size_t)q * 1024);
            v1 = *(const s16x8*)(vbase + 16 + (size_t)(q + 32) * 1024);
            oLo = __builtin_amdgcn_mfma_f32_32x32x16_bf16(paA1, v0, oLo, 0, 0, 0);
            oHi = __builtin_amdgcn_mfma_f32_32x32x16_bf16(paA1, v1, oHi, 0, 0, 0);
            v0 = *(const s16x8*)(vbase + 32 + (size_t)q * 1024);
            v1 = *(const s16x8*)(vbase + 32 + (size_t)(q + 32) * 1024);
            oLo = __builtin_amdgcn_mfma_f32_32x32x16_bf16(paB0, v0, oLo, 0, 0, 0);
            oHi = __builtin_amdgcn_mfma_f32_32x32x16_bf16(paB0, v1, oHi, 0, 0, 0);
            v0 = *(const s16x8*)(vbase + 48 + (size_t)q * 1024);
            v1 = *(const s16x8*)(vbase + 48 + (size_t)(q + 32) * 1024);
            oLo = __builtin_amdgcn_mfma_f32_32x32x16_bf16(paB1, v0, oLo, 0, 0, 0);
            oHi = __builtin_amdgcn_mfma_f32_32x32x16_bf16(paB1, v1, oHi, 0, 0, 0);
        }
        oLo = oLo * scown;
        oHi = oHi * scown;
        // ---- cross-wave O reduce: hi-waves write, lo-waves RMW, all read ----
        if (w >= 8) {
            const int ws = w - 8;
#pragma unroll
            for (int r = 0; r < 16; ++r) {
                int qq = (r & 3) + 8 * (r >> 2) + 4 * hi;
                slab[ws][qq][q] = oLo[r];
                slab[ws][qq][q + 32] = oHi[r];
            }
        }
        __syncthreads();                      // SYNC_B1
        if (w < 8) {
#pragma unroll
            for (int r = 0; r < 16; ++r) {
                int qq = (r & 3) + 8 * (r >> 2) + 4 * hi;
                slab[w][qq][q] += oLo[r];
                slab[w][qq][q + 32] += oHi[r];
            }
        }
        __syncthreads();                      // SYNC_B2
        {
            const int qo = t >> 5, dd = (t & 31) * 2;
            float ax = 0.f, ay = 0.f;
#pragma unroll
            for (int ws = 0; ws < 8; ++ws) {
                float2 v2 = *(const float2*)&slab[ws][qo][dd];
                ax += v2.x; ay += v2.y;
            }
            u32 pk = (u32)f2bf(ax) | ((u32)f2bf(ay) << 16);
            *(u32*)(og + (size_t)(b * 1024 + q0 + qo) * 1024 + h * 64 + dd) = pk;
        }
    }
    // ---- write head-averaged attention weights from registers ----
    float* awrow = aw + (size_t)(b * 1024 + q0 + q) * 1024 + kslice;
#pragma unroll
    for (int rg = 0; rg < 4; ++rg) {
        float4 vA = make_float4(awA[rg * 4 + 0], awA[rg * 4 + 1],
                                awA[rg * 4 + 2], awA[rg * 4 + 3]);
        float4 vB = make_float4(awB[rg * 4 + 0], awB[rg * 4 + 1],
                                awB[rg * 4 + 2], awB[rg * 4 + 3]);
        *(float4*)(awrow + 8 * rg + 4 * hi) = vA;
        *(float4*)(awrow + 32 + 8 * rg + 4 * hi) = vB;
    }
}

// ---------------------------------------------------------------------------
// Clustering stage A: per-row bitmask of (aw > 0.5) via ballot.
// ---------------------------------------------------------------------------
__global__ __launch_bounds__(256) void mask_kernel(const float* __restrict__ aw,
                                                   u64* __restrict__ maskg) {
    const int t = threadIdx.x;
    const int b = blockIdx.y;
    const int i0 = blockIdx.x * 64;
    const int wv = t >> 6, lane = t & 63;
    for (int rr = 0; rr < 16; ++rr) {
        int i = i0 + wv * 16 + rr;
        const float* row = aw + (size_t)(b * S + i) * S;
#pragma unroll
        for (int jj = 0; jj < 16; ++jj) {
            u64 bal = __ballot(row[lane + 64 * jj] > 0.5f);
            if (lane == 0) maskg[(size_t)(b * S + i) * 16 + jj] = bal;
        }
    }
}

// ---------------------------------------------------------------------------
// Clustering stage B: sequential greedy scan over NONEMPTY rows only
// (rows with no bit > threshold claim nothing -> skipping them is exact).
// ---------------------------------------------------------------------------
__global__ __launch_bounds__(256) void cluster_kernel(
    const u64* __restrict__ maskg, float* __restrict__ cid, u64* __restrict__ cov) {
    __shared__ u64 mask[16384];
    __shared__ u16 rows[1024];
    const int t = threadIdx.x;
    const int b = blockIdx.x;
#pragma unroll
    for (int i = 0; i < 64; ++i)
        mask[t + 256 * i] = maskg[(size_t)b * 16384 + t + 256 * i];
#pragma unroll
    for (int i = 0; i < 4; ++i) cid[b * S + t + 256 * i] = -1.0f;
    __syncthreads();
    if (t < 64) {
        // ordered compaction of nonempty rows (wave 0 only)
        int nr = 0;
        for (int it = 0; it < 16; ++it) {
            int row = it * 64 + t;
            const u64* mp = mask + row * 16;
            u64 orv = 0;
#pragma unroll
            for (int j = 0; j < 16; ++j) orv |= mp[j];
            u64 bal = __ballot(orv != 0ULL);
            int pre = __popcll(bal & ((1ULL << t) - 1ULL));
            if (orv != 0ULL) rows[nr + pre] = (u16)row;
            nr += __popcll(bal);
        }
        u64 vis = 0;
        for (int idx = 0; idx < nr; ++idx) {
            int i = rows[idx];
            u64 viw = __shfl(vis, i >> 6);
            bool proc = ((viw >> (i & 63)) & 1ULL) == 0ULL;
            u64 cl = (proc && t < 16) ? mask[i * 16 + t] : 0ULL;
            u64 newly = cl & ~vis;
            vis |= cl;
            while (newly) {
                int bit = __ffsll((long long)newly) - 1;
                cid[b * S + t * 64 + bit] = (float)i;
                newly &= newly - 1;
            }
        }
        if (t < 16) cov[b * 16 + t] = vis;
    }
}

// ---------------------------------------------------------------------------
// clustered_outputs = covered ? x : -1e9
// ---------------------------------------------------------------------------
__global__ __launch_bounds__(256) void clustered_kernel(
    const float* __restrict__ x, const u64* __restrict__ cov,
    float* __restrict__ out2) {
    const size_t n4 = (size_t)B * S * E / 4;
    size_t idx = (size_t)blockIdx.x * 256 + threadIdx.x;
    const float4 neg = make_float4(-1e9f, -1e9f, -1e9f, -1e9f);
    for (; idx < n4; idx += (size_t)gridDim.x * 256) {
        size_t tok = idx >> 8;
        int bb = (int)(tok >> 10), s = (int)(tok & 1023);
        u64 m = cov[bb * 16 + (s >> 6)];
        bool c = ((m >> (s & 63)) & 1ULL) != 0ULL;
        float4 v = ((const float4*)x)[idx];
        ((float4*)out2)[idx] = c ? v : neg;
    }
}

extern "C" void kernel_launch(void* const* d_in, const int* in_sizes, int n_in,
                              void* d_out, int out_size, void* d_ws, size_t ws_size,
                              hipStream_t stream) {
    const float* x = (const float*)d_in[0];
    const float* w_in = (const float*)d_in[1];
    const float* b_in = (const float*)d_in[2];
    const float* w_out = (const float*)d_in[3];
    const float* b_out = (const float*)d_in[4];

    float* out0 = (float*)d_out;        // attn_output  [8,1024,1024]
    float* out1 = out0 + 8388608;       // attn_weights [8,1024,1024]
    float* out2 = out1 + 8388608;       // clustered    [8,1024,1024]
    float* out3 = out2 + 8388608;       // cluster_ids  [8,1024] (as float)

    // bf16 staging (all regions dead before their final output is written):
    u16* q_bf = (u16*)out0;             // [B,H,S,64]
    u16* vt_bf = q_bf + 8388608;        // [B,H,64,S]  (transposed V)
    u16* xb = (u16*)out1;               // x as bf16
    u16* k_bf = (u16*)out2;             // [B,H,S,64]
    u16* wb0 = k_bf + 8388608;          // W_in bf16 [3072][1024]
    u16* wb1 = wb0 + 3145728;           // W_out bf16 [1024][1024]
    u16* o_bf = (u16*)d_ws;             // attention output bf16 [B,S,E]
    u64* maskg = (u64*)((char*)d_ws + (size_t)(16u << 20));
    u64* cov = (u64*)((char*)d_ws + (size_t)(17u << 20));

    cvt_kernel<<<8192, 256, 0, stream>>>(x, xb, 2097152);
    cvt_kernel<<<3072, 256, 0, stream>>>(w_in, wb0, 786432);
    cvt_kernel<<<1024, 256, 0, stream>>>(w_out, wb1, 262144);

    mfma_gemm<0><<<dim3(64, 24), 256, 0, stream>>>(xb, wb0, b_in, q_bf, k_bf,
                                                   vt_bf, nullptr);
    attn_mfma<<<dim3(32, 8), 1024, 0, stream>>>(q_bf, k_bf, vt_bf, out1, o_bf);
    mfma_gemm<1><<<dim3(64, 8), 256, 0, stream>>>(o_bf, wb1, b_out, nullptr,
                                                  nullptr, nullptr, out0);

    mask_kernel<<<dim3(16, 8), 256, 0, stream>>>(out1, maskg);
    cluster_kernel<<<8, 256, 0, stream>>>(maskg, out3, cov);
    clustered_kernel<<<2048, 256, 0, stream>>>(x, cov, out2);
}

// Round 4
// 359.513 us; speedup vs baseline: 13.0024x; 1.1738x over previous
//
#include <hip/hip_runtime.h>
#include <hip/hip_bf16.h>

#define B 8
#define S 1024
#define E 1024
#define H 16

typedef unsigned short u16;
typedef unsigned int u32;
typedef unsigned long long u64;

typedef __attribute__((ext_vector_type(8))) short s16x8;
typedef __attribute__((ext_vector_type(4))) float f32x4;
typedef __attribute__((ext_vector_type(16))) float f32x16;

__device__ __forceinline__ float bf2f(u16 u) {
    union { u32 i; float f; } x; x.i = ((u32)u) << 16; return x.f;
}
__device__ __forceinline__ u16 f2bf(float f) {
    union { float f; u32 i; } x; x.f = f;
    u32 r = x.i + 0x7FFFu + ((x.i >> 16) & 1u);
    return (u16)(r >> 16);
}
__device__ __forceinline__ f32x16 zero16() {
    f32x16 z;
#pragma unroll
    for (int i = 0; i < 16; ++i) z[i] = 0.f;
    return z;
}

// ---------------------------------------------------------------------------
// fp32 -> bf16 conversion (x, W_in, W_out)
// ---------------------------------------------------------------------------
__global__ __launch_bounds__(256) void cvt_kernel(const float* __restrict__ in,
                                                  u16* __restrict__ out, int n4) {
    int i = blockIdx.x * 256 + threadIdx.x;
    if (i < n4) {
        float4 v = ((const float4*)in)[i];
        union { u16 u[4]; ushort4 s; } p;
        p.u[0] = f2bf(v.x); p.u[1] = f2bf(v.y);
        p.u[2] = f2bf(v.z); p.u[3] = f2bf(v.w);
        ((ushort4*)out)[i] = p.s;
    }
}

// ---------------------------------------------------------------------------
// MFMA GEMM (q output pre-scaled by 1/8 so attention needs no score scaling).
// ---------------------------------------------------------------------------
template <int MODE>
__global__ __launch_bounds__(256) void mfma_gemm(
    const u16* __restrict__ A, const u16* __restrict__ W,
    const float* __restrict__ bias, u16* __restrict__ qb, u16* __restrict__ kb,
    u16* __restrict__ vt, float* __restrict__ outf) {
    __shared__ u16 As[128 * 72];
    __shared__ u16 Bs[128 * 72];
    const int t = threadIdx.x;
    const int lane = t & 63;
    const int w = t >> 6;
    const int m0 = blockIdx.x * 128;
    const int n0 = blockIdx.y * 128;
    const int wm = w >> 1, wn = w & 1;
    const int l15 = lane & 15, l4 = lane >> 4;

    f32x4 acc[4][4];
#pragma unroll
    for (int i = 0; i < 4; ++i)
#pragma unroll
        for (int j = 0; j < 4; ++j) acc[i][j] = {0.f, 0.f, 0.f, 0.f};

    for (int k0 = 0; k0 < 1024; k0 += 64) {
        __syncthreads();
#pragma unroll
        for (int i = 0; i < 4; ++i) {
            int slot = i * 256 + t;
            int row = slot >> 3, seg = slot & 7;
            s16x8 va = *(const s16x8*)(A + (size_t)(m0 + row) * 1024 + k0 + seg * 8);
            s16x8 vb = *(const s16x8*)(W + (size_t)(n0 + row) * 1024 + k0 + seg * 8);
            *(s16x8*)(As + row * 72 + seg * 8) = va;
            *(s16x8*)(Bs + row * 72 + seg * 8) = vb;
        }
        __syncthreads();
#pragma unroll
        for (int ks = 0; ks < 2; ++ks) {
            s16x8 af[4], bf[4];
#pragma unroll
            for (int i = 0; i < 4; ++i)
                af[i] = *(const s16x8*)(As + (wm * 64 + i * 16 + l15) * 72 + ks * 32 + l4 * 8);
#pragma unroll
            for (int j = 0; j < 4; ++j)
                bf[j] = *(const s16x8*)(Bs + (wn * 64 + j * 16 + l15) * 72 + ks * 32 + l4 * 8);
#pragma unroll
            for (int i = 0; i < 4; ++i)
#pragma unroll
                for (int j = 0; j < 4; ++j)
                    acc[i][j] = __builtin_amdgcn_mfma_f32_16x16x32_bf16(
                        af[i], bf[j], acc[i][j], 0, 0, 0);
        }
    }

    if (MODE == 0) {
#pragma unroll
        for (int j = 0; j < 4; ++j) {
            int n = n0 + wn * 64 + j * 16 + l15;
            float bn = bias[n];
            int seg = n >> 10;
            int e = n & 1023;
            int hh = e >> 6, d = e & 63;
            float sc = (seg == 0) ? 0.125f : 1.0f;
#pragma unroll
            for (int i = 0; i < 4; ++i) {
                int mbase = m0 + wm * 64 + i * 16 + l4 * 4;
                int bb = mbase >> 10, sb = mbase & 1023;
                if (seg == 2) {
                    union { u16 u[4]; ushort4 s; } p;
#pragma unroll
                    for (int rr = 0; rr < 4; ++rr) p.u[rr] = f2bf(acc[i][j][rr] + bn);
                    *(ushort4*)(vt + ((size_t)(bb * 16 + hh) * 64 + d) * 1024 + sb) = p.s;
                } else {
                    u16* dst = (seg == 0) ? qb : kb;
#pragma unroll
                    for (int rr = 0; rr < 4; ++rr)
                        dst[((size_t)(bb * 16 + hh) * 1024 + sb + rr) * 64 + d] =
                            f2bf((acc[i][j][rr] + bn) * sc);
                }
            }
        }
    } else {
#pragma unroll
        for (int j = 0; j < 4; ++j) {
            int n = n0 + wn * 64 + j * 16 + l15;
            float bn = bias[n];
#pragma unroll
            for (int i = 0; i < 4; ++i) {
                int mbase = m0 + wm * 64 + i * 16 + l4 * 4;
#pragma unroll
                for (int rr = 0; rr < 4; ++rr)
                    outf[(size_t)(mbase + rr) * 1024 + n] = acc[i][j][rr] + bn;
            }
        }
    }
}

// ---------------------------------------------------------------------------
// build PV fragment from 8 exp-values (T12: cvt_pk + permlane32_swap).
// Result layout: lane holds 8 contiguous k at k = (lane>>5)*8 + j.
// ---------------------------------------------------------------------------
template <int BASE>
__device__ __forceinline__ s16x8 build_pa(f32x16 e) {
    u32 a, bv, c, d;
    asm("v_cvt_pk_bf16_f32 %0, %1, %2" : "=v"(a) : "v"(e[BASE + 0]), "v"(e[BASE + 1]));
    asm("v_cvt_pk_bf16_f32 %0, %1, %2" : "=v"(bv) : "v"(e[BASE + 2]), "v"(e[BASE + 3]));
    asm("v_cvt_pk_bf16_f32 %0, %1, %2" : "=v"(c) : "v"(e[BASE + 4]), "v"(e[BASE + 5]));
    asm("v_cvt_pk_bf16_f32 %0, %1, %2" : "=v"(d) : "v"(e[BASE + 6]), "v"(e[BASE + 7]));
    asm("v_permlane32_swap_b32 %0, %1" : "+v"(a), "+v"(c));
    asm("v_permlane32_swap_b32 %0, %1" : "+v"(bv), "+v"(d));
    union { u32 w[4]; s16x8 v; } u;
    u.w[0] = a; u.w[1] = bv; u.w[2] = c; u.w[3] = d;
    return u.v;
}
// partner-combine helpers (lane i <-> lane i^32)
__device__ __forceinline__ float pair_max(float v) {
    float a_ = v, b_ = v;
    asm("v_permlane32_swap_b32 %0, %1" : "+v"(a_), "+v"(b_));
    return fmaxf(a_, b_);
}
__device__ __forceinline__ float pair_sum(float v) {
    float a_ = v, b_ = v;
    asm("v_permlane32_swap_b32 %0, %1" : "+v"(a_), "+v"(b_));
    return a_ + b_;
}
__device__ __forceinline__ u32 pair_or(u32 v) {
    u32 a_ = v, b_ = v;
    asm("v_permlane32_swap_b32 %0, %1" : "+v"(a_), "+v"(b_));
    return a_ | b_;
}

// ---------------------------------------------------------------------------
// Flash attention, one wave per (b, h, q-tile of 32). Zero barriers, zero LDS.
// Swapped QK^T: scores C[k][q], lane owns col q=lane&31. Online softmax with
// defer-max (THR=8). PV computed transposed: O^T = mfma(A=V^T, B=P) so O cols
// are q=lane&31 -> stats/rescale lane-aligned. Writes o_bf and {m, 1/(16 l)}.
// ---------------------------------------------------------------------------
__global__ __launch_bounds__(256) void attn_flash(
    const u16* __restrict__ qg, const u16* __restrict__ kg,
    const u16* __restrict__ vtg, u16* __restrict__ og,
    float2* __restrict__ stats) {
    const int t = threadIdx.x;
    const int lane = t & 63;
    const int wid = blockIdx.x * 4 + (t >> 6);
    const int qt = wid & 31;
    const int h = (wid >> 5) & 15;
    const int b = wid >> 9;
    const int q = lane & 31;
    const int hi = lane >> 5;
    const int q0 = qt * 32;
    const size_t hb = (size_t)(b * 16 + h) << 16;   // * S * 64

    // Q fragments (pre-scaled by 1/8 in GEMM epilogue)
    s16x8 qf[4];
#pragma unroll
    for (int s = 0; s < 4; ++s)
        qf[s] = *(const s16x8*)(qg + hb + (size_t)(q0 + q) * 64 + s * 16 + hi * 8);

    f32x16 oLo = zero16(), oHi = zero16();
    float m = -1e30f, l = 0.f;

    for (int ch = 0; ch < 1024; ch += 64) {
        // ---- QK^T: two 32-row K tiles ----
        f32x16 sA = zero16(), sB = zero16();
        {
            const u16* kp = kg + hb + (size_t)(ch + q) * 64 + hi * 8;
#pragma unroll
            for (int s = 0; s < 4; ++s) {
                s16x8 ka = *(const s16x8*)(kp + s * 16);
                sA = __builtin_amdgcn_mfma_f32_32x32x16_bf16(ka, qf[s], sA, 0, 0, 0);
            }
            kp += 32 * 64;
#pragma unroll
            for (int s = 0; s < 4; ++s) {
                s16x8 ka = *(const s16x8*)(kp + s * 16);
                sB = __builtin_amdgcn_mfma_f32_32x32x16_bf16(ka, qf[s], sB, 0, 0, 0);
            }
        }
        // ---- chunk max (in-lane + partner) ----
        float m0 = -1e30f, m1 = -1e30f, m2 = -1e30f, m3 = -1e30f;
#pragma unroll
        for (int i = 0; i < 16; i += 4) {
            m0 = fmaxf(m0, fmaxf(sA[i + 0], sB[i + 0]));
            m1 = fmaxf(m1, fmaxf(sA[i + 1], sB[i + 1]));
            m2 = fmaxf(m2, fmaxf(sA[i + 2], sB[i + 2]));
            m3 = fmaxf(m3, fmaxf(sA[i + 3], sB[i + 3]));
        }
        float pmax = pair_max(fmaxf(fmaxf(m0, m1), fmaxf(m2, m3)));
        // ---- defer-max rescale (rare) ----
        if (__any(pmax > m + 8.0f)) {
            float r = (pmax > m + 8.0f) ? __expf(m - pmax) : 1.0f;
            m = fmaxf(m, pmax);
            l *= r;
            oLo = oLo * r;
            oHi = oHi * r;
        }
        // ---- exp + row-sum ----
        float s0 = 0.f, s1 = 0.f, s2 = 0.f, s3 = 0.f;
#pragma unroll
        for (int i = 0; i < 16; i += 4) {
            sA[i + 0] = __expf(sA[i + 0] - m); sB[i + 0] = __expf(sB[i + 0] - m);
            sA[i + 1] = __expf(sA[i + 1] - m); sB[i + 1] = __expf(sB[i + 1] - m);
            sA[i + 2] = __expf(sA[i + 2] - m); sB[i + 2] = __expf(sB[i + 2] - m);
            sA[i + 3] = __expf(sA[i + 3] - m); sB[i + 3] = __expf(sB[i + 3] - m);
            s0 += sA[i + 0] + sB[i + 0]; s1 += sA[i + 1] + sB[i + 1];
            s2 += sA[i + 2] + sB[i + 2]; s3 += sA[i + 3] + sB[i + 3];
        }
        l += pair_sum((s0 + s1) + (s2 + s3));
        // ---- P fragments (B-operand layout) ----
        s16x8 paA0 = build_pa<0>(sA), paA1 = build_pa<8>(sA);
        s16x8 paB0 = build_pa<0>(sB), paB1 = build_pa<8>(sB);
        // ---- PV (transposed): A = V^T rows d, B = P; C[d][q] ----
        const u16* vb0 = vtg + hb + (size_t)q * 1024 + ch + hi * 8;          // d = q
        const u16* vb1 = vtg + hb + (size_t)(q + 32) * 1024 + ch + hi * 8;   // d = q+32
        oLo = __builtin_amdgcn_mfma_f32_32x32x16_bf16(*(const s16x8*)(vb0), paA0, oLo, 0, 0, 0);
        oHi = __builtin_amdgcn_mfma_f32_32x32x16_bf16(*(const s16x8*)(vb1), paA0, oHi, 0, 0, 0);
        oLo = __builtin_amdgcn_mfma_f32_32x32x16_bf16(*(const s16x8*)(vb0 + 16), paA1, oLo, 0, 0, 0);
        oHi = __builtin_amdgcn_mfma_f32_32x32x16_bf16(*(const s16x8*)(vb1 + 16), paA1, oHi, 0, 0, 0);
        oLo = __builtin_amdgcn_mfma_f32_32x32x16_bf16(*(const s16x8*)(vb0 + 32), paB0, oLo, 0, 0, 0);
        oHi = __builtin_amdgcn_mfma_f32_32x32x16_bf16(*(const s16x8*)(vb1 + 32), paB0, oHi, 0, 0, 0);
        oLo = __builtin_amdgcn_mfma_f32_32x32x16_bf16(*(const s16x8*)(vb0 + 48), paB1, oLo, 0, 0, 0);
        oHi = __builtin_amdgcn_mfma_f32_32x32x16_bf16(*(const s16x8*)(vb1 + 48), paB1, oHi, 0, 0, 0);
    }
    // ---- normalize + store o (bf16) ----
    float inv = 1.0f / l;
    oLo = oLo * inv;
    oHi = oHi * inv;
    u16* orow = og + (size_t)(b * 1024 + q0 + q) * 1024 + h * 64;
#pragma unroll
    for (int rg = 0; rg < 4; ++rg) {
        union { u16 u[4]; u64 v; } pk;
#pragma unroll
        for (int j = 0; j < 4; ++j) pk.u[j] = f2bf(oLo[4 * rg + j]);
        *(u64*)(orow + 8 * rg + 4 * hi) = pk.v;
#pragma unroll
        for (int j = 0; j < 4; ++j) pk.u[j] = f2bf(oHi[4 * rg + j]);
        *(u64*)(orow + 32 + 8 * rg + 4 * hi) = pk.v;
    }
    if (hi == 0)
        stats[(size_t)(b * 16 + h) * 1024 + q0 + q] = make_float2(m, 0.0625f * inv);
}

// ---------------------------------------------------------------------------
// attn_weights: one wave per (b, q-tile 32, k-slice 64), loops 16 heads.
// Recomputes QK^T, applies exp(s-m)*inv16L with attn_flash's exact stats,
// accumulates head-mean aw in registers; writes aw + fused >0.5 bitmask.
// ---------------------------------------------------------------------------
__global__ __launch_bounds__(256) void attn_aw(
    const u16* __restrict__ qg, const u16* __restrict__ kg,
    const float2* __restrict__ stats, float* __restrict__ aw,
    u64* __restrict__ maskg) {
    const int t = threadIdx.x;
    const int lane = t & 63;
    const int wid = blockIdx.x * 4 + (t >> 6);
    const int qt = wid & 31;
    const int ks = (wid >> 5) & 15;
    const int b = wid >> 9;
    const int q = lane & 31;
    const int hi = lane >> 5;
    const int q0 = qt * 32;
    const int kbase = ks * 64;

    f32x16 awA = zero16(), awB = zero16();

    for (int h = 0; h < 16; ++h) {
        const size_t hb = (size_t)(b * 16 + h) << 16;
        s16x8 qf[4];
#pragma unroll
        for (int s = 0; s < 4; ++s)
            qf[s] = *(const s16x8*)(qg + hb + (size_t)(q0 + q) * 64 + s * 16 + hi * 8);
        f32x16 sA = zero16(), sB = zero16();
        {
            const u16* kp = kg + hb + (size_t)(kbase + q) * 64 + hi * 8;
#pragma unroll
            for (int s = 0; s < 4; ++s) {
                s16x8 ka = *(const s16x8*)(kp + s * 16);
                sA = __builtin_amdgcn_mfma_f32_32x32x16_bf16(ka, qf[s], sA, 0, 0, 0);
            }
            kp += 32 * 64;
#pragma unroll
            for (int s = 0; s < 4; ++s) {
                s16x8 ka = *(const s16x8*)(kp + s * 16);
                sB = __builtin_amdgcn_mfma_f32_32x32x16_bf16(ka, qf[s], sB, 0, 0, 0);
            }
        }
        float2 st = stats[(size_t)(b * 16 + h) * 1024 + q0 + q];
        const float mh = st.x, f = st.y;
#pragma unroll
        for (int i = 0; i < 16; ++i) {
            awA[i] += __expf(sA[i] - mh) * f;
            awB[i] += __expf(sB[i] - mh) * f;
        }
    }
    // ---- write aw (rows q0+q, cols kbase + k_r) ----
    float* awrow = aw + (size_t)(b * 1024 + q0 + q) * 1024 + kbase;
#pragma unroll
    for (int rg = 0; rg < 4; ++rg) {
        *(float4*)(awrow + 8 * rg + 4 * hi) =
            make_float4(awA[4 * rg + 0], awA[4 * rg + 1], awA[4 * rg + 2], awA[4 * rg + 3]);
        *(float4*)(awrow + 32 + 8 * rg + 4 * hi) =
            make_float4(awB[4 * rg + 0], awB[4 * rg + 1], awB[4 * rg + 2], awB[4 * rg + 3]);
    }
    // ---- fused >0.5 mask ----
    u32 lo = 0, hi32 = 0;
#pragma unroll
    for (int r = 0; r < 16; ++r) {
        int k = (r & 3) + 8 * (r >> 2) + 4 * hi;
        lo |= (awA[r] > 0.5f) ? (1u << k) : 0u;
        hi32 |= (awB[r] > 0.5f) ? (1u << k) : 0u;
    }
    lo = pair_or(lo);
    hi32 = pair_or(hi32);
    if (hi == 0)
        maskg[(size_t)(b * 1024 + q0 + q) * 16 + ks] = ((u64)hi32 << 32) | (u64)lo;
}

// ---------------------------------------------------------------------------
// Clustering: sequential greedy scan over NONEMPTY rows only.
// ---------------------------------------------------------------------------
__global__ __launch_bounds__(256) void cluster_kernel(
    const u64* __restrict__ maskg, float* __restrict__ cid, u64* __restrict__ cov) {
    __shared__ u64 mask[16384];
    __shared__ u16 rows[1024];
    const int t = threadIdx.x;
    const int b = blockIdx.x;
#pragma unroll
    for (int i = 0; i < 64; ++i)
        mask[t + 256 * i] = maskg[(size_t)b * 16384 + t + 256 * i];
#pragma unroll
    for (int i = 0; i < 4; ++i) cid[b * S + t + 256 * i] = -1.0f;
    __syncthreads();
    if (t < 64) {
        int nr = 0;
        for (int it = 0; it < 16; ++it) {
            int row = it * 64 + t;
            const u64* mp = mask + row * 16;
            u64 orv = 0;
#pragma unroll
            for (int j = 0; j < 16; ++j) orv |= mp[j];
            u64 bal = __ballot(orv != 0ULL);
            int pre = __popcll(bal & ((1ULL << t) - 1ULL));
            if (orv != 0ULL) rows[nr + pre] = (u16)row;
            nr += __popcll(bal);
        }
        u64 vis = 0;
        for (int idx = 0; idx < nr; ++idx) {
            int i = rows[idx];
            u64 viw = __shfl(vis, i >> 6);
            bool proc = ((viw >> (i & 63)) & 1ULL) == 0ULL;
            u64 cl = (proc && t < 16) ? mask[i * 16 + t] : 0ULL;
            u64 newly = cl & ~vis;
            vis |= cl;
            while (newly) {
                int bit = __ffsll((long long)newly) - 1;
                cid[b * S + t * 64 + bit] = (float)i;
                newly &= newly - 1;
            }
        }
        if (t < 16) cov[b * 16 + t] = vis;
    }
}

// ---------------------------------------------------------------------------
// clustered_outputs = covered ? x : -1e9
// ---------------------------------------------------------------------------
__global__ __launch_bounds__(256) void clustered_kernel(
    const float* __restrict__ x, const u64* __restrict__ cov,
    float* __restrict__ out2) {
    const size_t n4 = (size_t)B * S * E / 4;
    size_t idx = (size_t)blockIdx.x * 256 + threadIdx.x;
    const float4 neg = make_float4(-1e9f, -1e9f, -1e9f, -1e9f);
    for (; idx < n4; idx += (size_t)gridDim.x * 256) {
        size_t tok = idx >> 8;
        int bb = (int)(tok >> 10), s = (int)(tok & 1023);
        u64 m = cov[bb * 16 + (s >> 6)];
        bool c = ((m >> (s & 63)) & 1ULL) != 0ULL;
        float4 v = ((const float4*)x)[idx];
        ((float4*)out2)[idx] = c ? v : neg;
    }
}

extern "C" void kernel_launch(void* const* d_in, const int* in_sizes, int n_in,
                              void* d_out, int out_size, void* d_ws, size_t ws_size,
                              hipStream_t stream) {
    const float* x = (const float*)d_in[0];
    const float* w_in = (const float*)d_in[1];
    const float* b_in = (const float*)d_in[2];
    const float* w_out = (const float*)d_in[3];
    const float* b_out = (const float*)d_in[4];

    float* out0 = (float*)d_out;        // attn_output  [8,1024,1024]
    float* out1 = out0 + 8388608;       // attn_weights [8,1024,1024]
    float* out2 = out1 + 8388608;       // clustered    [8,1024,1024]
    float* out3 = out2 + 8388608;       // cluster_ids  [8,1024] (as float)

    // bf16 staging (each region dead before its final output is written):
    u16* q_bf = (u16*)out0;             // [B,H,S,64]  (dies at gemm<1>)
    u16* vt_bf = q_bf + 8388608;        // [B,H,64,S]  transposed V
    u16* xb = (u16*)out1;               // x bf16      (dies at attn_aw)
    u16* k_bf = (u16*)out2;             // [B,H,S,64]  (dies at clustered)
    u16* wb0 = k_bf + 8388608;          // W_in bf16
    u16* wb1 = wb0 + 3145728;           // W_out bf16
    float2* stats = (float2*)(k_bf + 12582912);  // {m, 1/(16 l)} per (b,h,q)
    u16* o_bf = (u16*)d_ws;             // attention output bf16 [B,S,E] (16 MB)
    u64* maskg = (u64*)((char*)d_ws + (size_t)(16u << 20));
    u64* cov = (u64*)((char*)d_ws + (size_t)(17u << 20));

    cvt_kernel<<<8192, 256, 0, stream>>>(x, xb, 2097152);
    cvt_kernel<<<3072, 256, 0, stream>>>(w_in, wb0, 786432);
    cvt_kernel<<<1024, 256, 0, stream>>>(w_out, wb1, 262144);

    mfma_gemm<0><<<dim3(64, 24), 256, 0, stream>>>(xb, wb0, b_in, q_bf, k_bf,
                                                   vt_bf, nullptr);
    attn_flash<<<1024, 256, 0, stream>>>(q_bf, k_bf, vt_bf, o_bf, stats);
    attn_aw<<<1024, 256, 0, stream>>>(q_bf, k_bf, stats, out1, maskg);
    mfma_gemm<1><<<dim3(64, 8), 256, 0, stream>>>(o_bf, wb1, b_out, nullptr,
                                                  nullptr, nullptr, out0);

    cluster_kernel<<<8, 256, 0, stream>>>(maskg, out3, cov);
    clustered_kernel<<<2048, 256, 0, stream>>>(x, cov, out2);
}

// Round 5
// 352.873 us; speedup vs baseline: 13.2471x; 1.0188x over previous
//
#include <hip/hip_runtime.h>
#include <hip/hip_bf16.h>

#define B 8
#define S 1024
#define E 1024
#define H 16

typedef unsigned short u16;
typedef unsigned int u32;
typedef unsigned long long u64;

typedef __attribute__((ext_vector_type(8))) short s16x8;
typedef __attribute__((ext_vector_type(4))) float f32x4;
typedef __attribute__((ext_vector_type(16))) float f32x16;

__device__ __forceinline__ float bf2f(u16 u) {
    union { u32 i; float f; } x; x.i = ((u32)u) << 16; return x.f;
}
__device__ __forceinline__ u16 f2bf(float f) {
    union { float f; u32 i; } x; x.f = f;
    u32 r = x.i + 0x7FFFu + ((x.i >> 16) & 1u);
    return (u16)(r >> 16);
}
__device__ __forceinline__ f32x16 zero16() {
    f32x16 z;
#pragma unroll
    for (int i = 0; i < 16; ++i) z[i] = 0.f;
    return z;
}

// ---------------------------------------------------------------------------
// fp32 -> bf16 conversion (x, W_in, W_out)
// ---------------------------------------------------------------------------
__global__ __launch_bounds__(256) void cvt_kernel(const float* __restrict__ in,
                                                  u16* __restrict__ out, int n4) {
    int i = blockIdx.x * 256 + threadIdx.x;
    if (i < n4) {
        float4 v = ((const float4*)in)[i];
        union { u16 u[4]; ushort4 s; } p;
        p.u[0] = f2bf(v.x); p.u[1] = f2bf(v.y);
        p.u[2] = f2bf(v.z); p.u[3] = f2bf(v.w);
        ((ushort4*)out)[i] = p.s;
    }
}

// ---------------------------------------------------------------------------
// MFMA GEMM (q output pre-scaled by 1/8 so attention needs no score scaling).
// ---------------------------------------------------------------------------
template <int MODE>
__global__ __launch_bounds__(256) void mfma_gemm(
    const u16* __restrict__ A, const u16* __restrict__ W,
    const float* __restrict__ bias, u16* __restrict__ qb, u16* __restrict__ kb,
    u16* __restrict__ vt, float* __restrict__ outf) {
    __shared__ u16 As[128 * 72];
    __shared__ u16 Bs[128 * 72];
    const int t = threadIdx.x;
    const int lane = t & 63;
    const int w = t >> 6;
    const int m0 = blockIdx.x * 128;
    const int n0 = blockIdx.y * 128;
    const int wm = w >> 1, wn = w & 1;
    const int l15 = lane & 15, l4 = lane >> 4;

    f32x4 acc[4][4];
#pragma unroll
    for (int i = 0; i < 4; ++i)
#pragma unroll
        for (int j = 0; j < 4; ++j) acc[i][j] = {0.f, 0.f, 0.f, 0.f};

    for (int k0 = 0; k0 < 1024; k0 += 64) {
        __syncthreads();
#pragma unroll
        for (int i = 0; i < 4; ++i) {
            int slot = i * 256 + t;
            int row = slot >> 3, seg = slot & 7;
            s16x8 va = *(const s16x8*)(A + (size_t)(m0 + row) * 1024 + k0 + seg * 8);
            s16x8 vb = *(const s16x8*)(W + (size_t)(n0 + row) * 1024 + k0 + seg * 8);
            *(s16x8*)(As + row * 72 + seg * 8) = va;
            *(s16x8*)(Bs + row * 72 + seg * 8) = vb;
        }
        __syncthreads();
#pragma unroll
        for (int ks = 0; ks < 2; ++ks) {
            s16x8 af[4], bf[4];
#pragma unroll
            for (int i = 0; i < 4; ++i)
                af[i] = *(const s16x8*)(As + (wm * 64 + i * 16 + l15) * 72 + ks * 32 + l4 * 8);
#pragma unroll
            for (int j = 0; j < 4; ++j)
                bf[j] = *(const s16x8*)(Bs + (wn * 64 + j * 16 + l15) * 72 + ks * 32 + l4 * 8);
#pragma unroll
            for (int i = 0; i < 4; ++i)
#pragma unroll
                for (int j = 0; j < 4; ++j)
                    acc[i][j] = __builtin_amdgcn_mfma_f32_16x16x32_bf16(
                        af[i], bf[j], acc[i][j], 0, 0, 0);
        }
    }

    if (MODE == 0) {
#pragma unroll
        for (int j = 0; j < 4; ++j) {
            int n = n0 + wn * 64 + j * 16 + l15;
            float bn = bias[n];
            int seg = n >> 10;
            int e = n & 1023;
            int hh = e >> 6, d = e & 63;
            float sc = (seg == 0) ? 0.125f : 1.0f;
#pragma unroll
            for (int i = 0; i < 4; ++i) {
                int mbase = m0 + wm * 64 + i * 16 + l4 * 4;
                int bb = mbase >> 10, sb = mbase & 1023;
                if (seg == 2) {
                    union { u16 u[4]; ushort4 s; } p;
#pragma unroll
                    for (int rr = 0; rr < 4; ++rr) p.u[rr] = f2bf(acc[i][j][rr] + bn);
                    *(ushort4*)(vt + ((size_t)(bb * 16 + hh) * 64 + d) * 1024 + sb) = p.s;
                } else {
                    u16* dst = (seg == 0) ? qb : kb;
#pragma unroll
                    for (int rr = 0; rr < 4; ++rr)
                        dst[((size_t)(bb * 16 + hh) * 1024 + sb + rr) * 64 + d] =
                            f2bf((acc[i][j][rr] + bn) * sc);
                }
            }
        }
    } else {
#pragma unroll
        for (int j = 0; j < 4; ++j) {
            int n = n0 + wn * 64 + j * 16 + l15;
            float bn = bias[n];
#pragma unroll
            for (int i = 0; i < 4; ++i) {
                int mbase = m0 + wm * 64 + i * 16 + l4 * 4;
#pragma unroll
                for (int rr = 0; rr < 4; ++rr)
                    outf[(size_t)(mbase + rr) * 1024 + n] = acc[i][j][rr] + bn;
            }
        }
    }
}

// ---------------------------------------------------------------------------
// build PV fragment from 8 exp-values (T12: cvt_pk + permlane32_swap).
// ---------------------------------------------------------------------------
template <int BASE>
__device__ __forceinline__ s16x8 build_pa(f32x16 e) {
    u32 a, bv, c, d;
    asm("v_cvt_pk_bf16_f32 %0, %1, %2" : "=v"(a) : "v"(e[BASE + 0]), "v"(e[BASE + 1]));
    asm("v_cvt_pk_bf16_f32 %0, %1, %2" : "=v"(bv) : "v"(e[BASE + 2]), "v"(e[BASE + 3]));
    asm("v_cvt_pk_bf16_f32 %0, %1, %2" : "=v"(c) : "v"(e[BASE + 4]), "v"(e[BASE + 5]));
    asm("v_cvt_pk_bf16_f32 %0, %1, %2" : "=v"(d) : "v"(e[BASE + 6]), "v"(e[BASE + 7]));
    asm("v_permlane32_swap_b32 %0, %1" : "+v"(a), "+v"(c));
    asm("v_permlane32_swap_b32 %0, %1" : "+v"(bv), "+v"(d));
    union { u32 w[4]; s16x8 v; } u;
    u.w[0] = a; u.w[1] = bv; u.w[2] = c; u.w[3] = d;
    return u.v;
}
// partner-combine helpers (lane i <-> lane i^32)
__device__ __forceinline__ float pair_max(float v) {
    float a_ = v, b_ = v;
    asm("v_permlane32_swap_b32 %0, %1" : "+v"(a_), "+v"(b_));
    return fmaxf(a_, b_);
}
__device__ __forceinline__ float pair_sum(float v) {
    float a_ = v, b_ = v;
    asm("v_permlane32_swap_b32 %0, %1" : "+v"(a_), "+v"(b_));
    return a_ + b_;
}
__device__ __forceinline__ u32 pair_or(u32 v) {
    u32 a_ = v, b_ = v;
    asm("v_permlane32_swap_b32 %0, %1" : "+v"(a_), "+v"(b_));
    return a_ | b_;
}

// ---------------------------------------------------------------------------
// Flash attention, one wave per (b, h, q-tile 32). Zero barriers, zero LDS.
// 32-row K tiles, software-pipelined: prefetch next K tile into regs, V loads
// issued before softmax; branchless online rescale keeps one basic block.
// XCD swizzle: 8 blocks sharing one head's K/V stream land on one XCD.
// ---------------------------------------------------------------------------
__global__ __launch_bounds__(256, 4) void attn_flash(
    const u16* __restrict__ qg, const u16* __restrict__ kg,
    const u16* __restrict__ vtg, u16* __restrict__ og,
    float2* __restrict__ stats) {
    const int t = threadIdx.x;
    const int lane = t & 63;
    const int bid = ((blockIdx.x & 7) << 7) | (blockIdx.x >> 3);  // XCD grouping
    const int wid = bid * 4 + (t >> 6);
    const int qt = wid & 31;
    const int h = (wid >> 5) & 15;
    const int b = wid >> 9;
    const int q = lane & 31;
    const int hi = lane >> 5;
    const int q0 = qt * 32;
    const size_t hb = (size_t)(b * 16 + h) << 16;   // * S * 64

    // Q fragments (pre-scaled by 1/8 in GEMM epilogue)
    s16x8 qf[4];
#pragma unroll
    for (int s = 0; s < 4; ++s)
        qf[s] = *(const s16x8*)(qg + hb + (size_t)(q0 + q) * 64 + s * 16 + hi * 8);

    // preload K tile 0 (rows 0..31)
    s16x8 kc[4];
    {
        const u16* kp = kg + hb + (size_t)q * 64 + hi * 8;
#pragma unroll
        for (int s = 0; s < 4; ++s) kc[s] = *(const s16x8*)(kp + s * 16);
    }

    f32x16 oLo = zero16(), oHi = zero16();
    float m = -1e30f, l = 0.f;

    for (int tile = 0; tile < 32; ++tile) {
        // ---- prefetch next K tile (wraps to 0 on last iter; harmless) ----
        s16x8 kn[4];
        {
            const u16* kp = kg + hb + (size_t)(((tile + 1) & 31) * 32 + q) * 64 + hi * 8;
#pragma unroll
            for (int s = 0; s < 4; ++s) kn[s] = *(const s16x8*)(kp + s * 16);
        }
        // ---- V loads for current tile (drain under softmax VALU) ----
        const u16* vb0 = vtg + hb + (size_t)q * 1024 + tile * 32 + hi * 8;
        const u16* vb1 = vtg + hb + (size_t)(q + 32) * 1024 + tile * 32 + hi * 8;
        s16x8 v00 = *(const s16x8*)(vb0);
        s16x8 v01 = *(const s16x8*)(vb0 + 16);
        s16x8 v10 = *(const s16x8*)(vb1);
        s16x8 v11 = *(const s16x8*)(vb1 + 16);
        // ---- QK^T: C[k][q], lane owns col q ----
        f32x16 s_ = zero16();
#pragma unroll
        for (int s = 0; s < 4; ++s)
            s_ = __builtin_amdgcn_mfma_f32_32x32x16_bf16(kc[s], qf[s], s_, 0, 0, 0);
        // ---- tile max (in-lane + partner) ----
        float m0 = fmaxf(fmaxf(s_[0], s_[4]), fmaxf(s_[8], s_[12]));
        float m1 = fmaxf(fmaxf(s_[1], s_[5]), fmaxf(s_[9], s_[13]));
        float m2 = fmaxf(fmaxf(s_[2], s_[6]), fmaxf(s_[10], s_[14]));
        float m3 = fmaxf(fmaxf(s_[3], s_[7]), fmaxf(s_[11], s_[15]));
        float pmax = pair_max(fmaxf(fmaxf(m0, m1), fmaxf(m2, m3)));
        // ---- branchless online rescale ----
        float mn = fmaxf(m, pmax);
        float r = __expf(m - mn);   // first iter: exp(-1e30)=0
        m = mn;
        // ---- exp + row-sum ----
        float s0 = 0.f, s1 = 0.f, s2 = 0.f, s3 = 0.f;
#pragma unroll
        for (int i = 0; i < 16; i += 4) {
            s_[i + 0] = __expf(s_[i + 0] - m);
            s_[i + 1] = __expf(s_[i + 1] - m);
            s_[i + 2] = __expf(s_[i + 2] - m);
            s_[i + 3] = __expf(s_[i + 3] - m);
            s0 += s_[i + 0]; s1 += s_[i + 1]; s2 += s_[i + 2]; s3 += s_[i + 3];
        }
        l = l * r + pair_sum((s0 + s1) + (s2 + s3));
        oLo = oLo * r;
        oHi = oHi * r;
        // ---- P fragments + PV (transposed): C[d][q] ----
        s16x8 p0 = build_pa<0>(s_), p1 = build_pa<8>(s_);
        oLo = __builtin_amdgcn_mfma_f32_32x32x16_bf16(v00, p0, oLo, 0, 0, 0);
        oLo = __builtin_amdgcn_mfma_f32_32x32x16_bf16(v01, p1, oLo, 0, 0, 0);
        oHi = __builtin_amdgcn_mfma_f32_32x32x16_bf16(v10, p0, oHi, 0, 0, 0);
        oHi = __builtin_amdgcn_mfma_f32_32x32x16_bf16(v11, p1, oHi, 0, 0, 0);
        // ---- rotate prefetch ----
#pragma unroll
        for (int s = 0; s < 4; ++s) kc[s] = kn[s];
    }
    // ---- normalize + store o (bf16) ----
    float inv = 1.0f / l;
    oLo = oLo * inv;
    oHi = oHi * inv;
    u16* orow = og + (size_t)(b * 1024 + q0 + q) * 1024 + h * 64;
#pragma unroll
    for (int rg = 0; rg < 4; ++rg) {
        union { u16 u[4]; u64 v; } pk;
#pragma unroll
        for (int j = 0; j < 4; ++j) pk.u[j] = f2bf(oLo[4 * rg + j]);
        *(u64*)(orow + 8 * rg + 4 * hi) = pk.v;
#pragma unroll
        for (int j = 0; j < 4; ++j) pk.u[j] = f2bf(oHi[4 * rg + j]);
        *(u64*)(orow + 32 + 8 * rg + 4 * hi) = pk.v;
    }
    if (hi == 0)
        stats[(size_t)(b * 16 + h) * 1024 + q0 + q] = make_float2(m, 0.0625f / l);
}

// ---------------------------------------------------------------------------
// attn_weights: one wave per (b, q-tile 32, k-slice 64), loops 16 heads.
// Pipelined: prefetch next 32-row K tile while computing current.
// Applies exp(s-m)*inv16L with attn_flash's exact stats; writes aw + mask.
// ---------------------------------------------------------------------------
__global__ __launch_bounds__(256, 4) void attn_aw(
    const u16* __restrict__ qg, const u16* __restrict__ kg,
    const float2* __restrict__ stats, float* __restrict__ aw,
    u64* __restrict__ maskg) {
    const int t = threadIdx.x;
    const int lane = t & 63;
    const int bid = ((blockIdx.x & 7) << 7) | (blockIdx.x >> 3);  // XCD grouping
    const int wid = bid * 4 + (t >> 6);
    const int qt = wid & 31;
    const int ks = (wid >> 5) & 15;
    const int b = wid >> 9;
    const int q = lane & 31;
    const int hi = lane >> 5;
    const int q0 = qt * 32;
    const int kbase = ks * 64;

    f32x16 awA = zero16(), awB = zero16();

    // preload K tile (h=0, rows kbase..kbase+31)
    s16x8 kc[4];
    {
        const u16* kp = kg + ((size_t)(b * 16) << 16) + (size_t)(kbase + q) * 64 + hi * 8;
#pragma unroll
        for (int s = 0; s < 4; ++s) kc[s] = *(const s16x8*)(kp + s * 16);
    }

    for (int h = 0; h < 16; ++h) {
        const size_t hb = (size_t)(b * 16 + h) << 16;
        s16x8 qf[4];
#pragma unroll
        for (int s = 0; s < 4; ++s)
            qf[s] = *(const s16x8*)(qg + hb + (size_t)(q0 + q) * 64 + s * 16 + hi * 8);
        float2 st = stats[(size_t)(b * 16 + h) * 1024 + q0 + q];
        // ---- half 0: prefetch half 1 of same head ----
        s16x8 kn[4];
        {
            const u16* kp = kg + hb + (size_t)(kbase + 32 + q) * 64 + hi * 8;
#pragma unroll
            for (int s = 0; s < 4; ++s) kn[s] = *(const s16x8*)(kp + s * 16);
        }
        f32x16 s_ = zero16();
#pragma unroll
        for (int s = 0; s < 4; ++s)
            s_ = __builtin_amdgcn_mfma_f32_32x32x16_bf16(kc[s], qf[s], s_, 0, 0, 0);
#pragma unroll
        for (int i = 0; i < 16; ++i) awA[i] += __expf(s_[i] - st.x) * st.y;
#pragma unroll
        for (int s = 0; s < 4; ++s) kc[s] = kn[s];
        // ---- half 1: prefetch half 0 of next head (wraps; harmless) ----
        {
            const size_t hbn = (size_t)(b * 16 + ((h + 1) & 15)) << 16;
            const u16* kp = kg + hbn + (size_t)(kbase + q) * 64 + hi * 8;
#pragma unroll
            for (int s = 0; s < 4; ++s) kn[s] = *(const s16x8*)(kp + s * 16);
        }
        s_ = zero16();
#pragma unroll
        for (int s = 0; s < 4; ++s)
            s_ = __builtin_amdgcn_mfma_f32_32x32x16_bf16(kc[s], qf[s], s_, 0, 0, 0);
#pragma unroll
        for (int i = 0; i < 16; ++i) awB[i] += __expf(s_[i] - st.x) * st.y;
#pragma unroll
        for (int s = 0; s < 4; ++s) kc[s] = kn[s];
    }
    // ---- write aw (rows q0+q, cols kbase + k_r) ----
    float* awrow = aw + (size_t)(b * 1024 + q0 + q) * 1024 + kbase;
#pragma unroll
    for (int rg = 0; rg < 4; ++rg) {
        *(float4*)(awrow + 8 * rg + 4 * hi) =
            make_float4(awA[4 * rg + 0], awA[4 * rg + 1], awA[4 * rg + 2], awA[4 * rg + 3]);
        *(float4*)(awrow + 32 + 8 * rg + 4 * hi) =
            make_float4(awB[4 * rg + 0], awB[4 * rg + 1], awB[4 * rg + 2], awB[4 * rg + 3]);
    }
    // ---- fused >0.5 mask ----
    u32 lo = 0, hi32 = 0;
#pragma unroll
    for (int r = 0; r < 16; ++r) {
        int k = (r & 3) + 8 * (r >> 2) + 4 * hi;
        lo |= (awA[r] > 0.5f) ? (1u << k) : 0u;
        hi32 |= (awB[r] > 0.5f) ? (1u << k) : 0u;
    }
    lo = pair_or(lo);
    hi32 = pair_or(hi32);
    if (hi == 0)
        maskg[(size_t)(b * 1024 + q0 + q) * 16 + ks] = ((u64)hi32 << 32) | (u64)lo;
}

// ---------------------------------------------------------------------------
// Clustering: sequential greedy scan over NONEMPTY rows only.
// ---------------------------------------------------------------------------
__global__ __launch_bounds__(256) void cluster_kernel(
    const u64* __restrict__ maskg, float* __restrict__ cid, u64* __restrict__ cov) {
    __shared__ u64 mask[16384];
    __shared__ u16 rows[1024];
    const int t = threadIdx.x;
    const int b = blockIdx.x;
#pragma unroll
    for (int i = 0; i < 64; ++i)
        mask[t + 256 * i] = maskg[(size_t)b * 16384 + t + 256 * i];
#pragma unroll
    for (int i = 0; i < 4; ++i) cid[b * S + t + 256 * i] = -1.0f;
    __syncthreads();
    if (t < 64) {
        int nr = 0;
        for (int it = 0; it < 16; ++it) {
            int row = it * 64 + t;
            const u64* mp = mask + row * 16;
            u64 orv = 0;
#pragma unroll
            for (int j = 0; j < 16; ++j) orv |= mp[j];
            u64 bal = __ballot(orv != 0ULL);
            int pre = __popcll(bal & ((1ULL << t) - 1ULL));
            if (orv != 0ULL) rows[nr + pre] = (u16)row;
            nr += __popcll(bal);
        }
        u64 vis = 0;
        for (int idx = 0; idx < nr; ++idx) {
            int i = rows[idx];
            u64 viw = __shfl(vis, i >> 6);
            bool proc = ((viw >> (i & 63)) & 1ULL) == 0ULL;
            u64 cl = (proc && t < 16) ? mask[i * 16 + t] : 0ULL;
            u64 newly = cl & ~vis;
            vis |= cl;
            while (newly) {
                int bit = __ffsll((long long)newly) - 1;
                cid[b * S + t * 64 + bit] = (float)i;
                newly &= newly - 1;
            }
        }
        if (t < 16) cov[b * 16 + t] = vis;
    }
}

// ---------------------------------------------------------------------------
// clustered_outputs = covered ? x : -1e9
// ---------------------------------------------------------------------------
__global__ __launch_bounds__(256) void clustered_kernel(
    const float* __restrict__ x, const u64* __restrict__ cov,
    float* __restrict__ out2) {
    const size_t n4 = (size_t)B * S * E / 4;
    size_t idx = (size_t)blockIdx.x * 256 + threadIdx.x;
    const float4 neg = make_float4(-1e9f, -1e9f, -1e9f, -1e9f);
    for (; idx < n4; idx += (size_t)gridDim.x * 256) {
        size_t tok = idx >> 8;
        int bb = (int)(tok >> 10), s = (int)(tok & 1023);
        u64 m = cov[bb * 16 + (s >> 6)];
        bool c = ((m >> (s & 63)) & 1ULL) != 0ULL;
        float4 v = ((const float4*)x)[idx];
        ((float4*)out2)[idx] = c ? v : neg;
    }
}

extern "C" void kernel_launch(void* const* d_in, const int* in_sizes, int n_in,
                              void* d_out, int out_size, void* d_ws, size_t ws_size,
                              hipStream_t stream) {
    const float* x = (const float*)d_in[0];
    const float* w_in = (const float*)d_in[1];
    const float* b_in = (const float*)d_in[2];
    const float* w_out = (const float*)d_in[3];
    const float* b_out = (const float*)d_in[4];

    float* out0 = (float*)d_out;        // attn_output  [8,1024,1024]
    float* out1 = out0 + 8388608;       // attn_weights [8,1024,1024]
    float* out2 = out1 + 8388608;       // clustered    [8,1024,1024]
    float* out3 = out2 + 8388608;       // cluster_ids  [8,1024] (as float)

    // bf16 staging (each region dead before its final output is written):
    u16* q_bf = (u16*)out0;             // [B,H,S,64]  (dies at gemm<1>)
    u16* vt_bf = q_bf + 8388608;        // [B,H,64,S]  transposed V
    u16* xb = (u16*)out1;               // x bf16      (dies at attn_aw)
    u16* k_bf = (u16*)out2;             // [B,H,S,64]  (dies at clustered)
    u16* wb0 = k_bf + 8388608;          // W_in bf16
    u16* wb1 = wb0 + 3145728;           // W_out bf16
    float2* stats = (float2*)(k_bf + 12582912);  // {m, 1/(16 l)} per (b,h,q)
    u16* o_bf = (u16*)d_ws;             // attention output bf16 [B,S,E] (16 MB)
    u64* maskg = (u64*)((char*)d_ws + (size_t)(16u << 20));
    u64* cov = (u64*)((char*)d_ws + (size_t)(17u << 20));

    cvt_kernel<<<8192, 256, 0, stream>>>(x, xb, 2097152);
    cvt_kernel<<<3072, 256, 0, stream>>>(w_in, wb0, 786432);
    cvt_kernel<<<1024, 256, 0, stream>>>(w_out, wb1, 262144);

    mfma_gemm<0><<<dim3(64, 24), 256, 0, stream>>>(xb, wb0, b_in, q_bf, k_bf,
                                                   vt_bf, nullptr);
    attn_flash<<<1024, 256, 0, stream>>>(q_bf, k_bf, vt_bf, o_bf, stats);
    attn_aw<<<1024, 256, 0, stream>>>(q_bf, k_bf, stats, out1, maskg);
    mfma_gemm<1><<<dim3(64, 8), 256, 0, stream>>>(o_bf, wb1, b_out, nullptr,
                                                  nullptr, nullptr, out0);

    cluster_kernel<<<8, 256, 0, stream>>>(maskg, out3, cov);
    clustered_kernel<<<2048, 256, 0, stream>>>(x, cov, out2);
}

// Round 6
// 303.232 us; speedup vs baseline: 15.4157x; 1.1637x over previous
//
#include <hip/hip_runtime.h>
#include <hip/hip_bf16.h>

#define B 8
#define S 1024
#define E 1024
#define H 16

typedef unsigned short u16;
typedef unsigned char u8;
typedef unsigned int u32;
typedef unsigned long long u64;

typedef __attribute__((ext_vector_type(8))) short s16x8;
typedef __attribute__((ext_vector_type(4))) float f32x4;
typedef __attribute__((ext_vector_type(16))) float f32x16;

__device__ __forceinline__ float bf2f(u16 u) {
    union { u32 i; float f; } x; x.i = ((u32)u) << 16; return x.f;
}
__device__ __forceinline__ u16 f2bf(float f) {
    union { float f; u32 i; } x; x.f = f;
    u32 r = x.i + 0x7FFFu + ((x.i >> 16) & 1u);
    return (u16)(r >> 16);
}
__device__ __forceinline__ f32x16 zero16() {
    f32x16 z;
#pragma unroll
    for (int i = 0; i < 16; ++i) z[i] = 0.f;
    return z;
}
// async global->LDS, 16B per lane; LDS dest = wave-uniform base + lane*16
__device__ __forceinline__ void gload16(const u16* g, u16* l) {
    __builtin_amdgcn_global_load_lds(
        (const __attribute__((address_space(1))) u32*)g,
        (__attribute__((address_space(3))) u32*)l, 16, 0, 0);
}

// ---------------------------------------------------------------------------
// fp32 -> bf16 conversion (x, W_in, W_out)
// ---------------------------------------------------------------------------
__global__ __launch_bounds__(256) void cvt_kernel(const float* __restrict__ in,
                                                  u16* __restrict__ out, int n4) {
    int i = blockIdx.x * 256 + threadIdx.x;
    if (i < n4) {
        float4 v = ((const float4*)in)[i];
        union { u16 u[4]; ushort4 s; } p;
        p.u[0] = f2bf(v.x); p.u[1] = f2bf(v.y);
        p.u[2] = f2bf(v.z); p.u[3] = f2bf(v.w);
        ((ushort4*)out)[i] = p.s;
    }
}

// ---------------------------------------------------------------------------
// MFMA GEMM, m97 structure: 128x128 tile, BK=64, linear LDS [128][64],
// global_load_lds width-16 staging, 2-barrier loop.
// MODE 0 (qkv, q pre-scaled 1/8): n<1024 -> q; n<2048 -> k; else vt (V^T).
// MODE 1: C fp32 -> outf.
// ---------------------------------------------------------------------------
template <int MODE>
__global__ __launch_bounds__(256) void mfma_gemm(
    const u16* __restrict__ A, const u16* __restrict__ W,
    const float* __restrict__ bias, u16* __restrict__ qb, u16* __restrict__ kb,
    u16* __restrict__ vt, float* __restrict__ outf) {
    __shared__ __align__(16) u16 As[128 * 64];
    __shared__ __align__(16) u16 Bs[128 * 64];
    const int t = threadIdx.x;
    const int lane = t & 63;
    const int w = t >> 6;
    const int m0 = blockIdx.x * 128;
    const int n0 = blockIdx.y * 128;
    const int wm = w >> 1, wn = w & 1;
    const int l15 = lane & 15, l4 = lane >> 4;
    const int lr = lane >> 3;          // row within an 8-row staging issue
    const int lc = (lane & 7) * 8;     // col (elems) within the row

    f32x4 acc[4][4];
#pragma unroll
    for (int i = 0; i < 4; ++i)
#pragma unroll
        for (int j = 0; j < 4; ++j) acc[i][j] = {0.f, 0.f, 0.f, 0.f};

    for (int k0 = 0; k0 < 1024; k0 += 64) {
        __syncthreads();
#pragma unroll
        for (int jj = 0; jj < 4; ++jj) {
            int j = w * 4 + jj;        // 16 issues of 1KB per operand
            gload16(A + (size_t)(m0 + j * 8 + lr) * 1024 + k0 + lc, As + j * 512);
            gload16(W + (size_t)(n0 + j * 8 + lr) * 1024 + k0 + lc, Bs + j * 512);
        }
        __syncthreads();   // compiler drains vmcnt before barrier -> data ready
#pragma unroll
        for (int ks = 0; ks < 2; ++ks) {
            s16x8 af[4], bf[4];
#pragma unroll
            for (int i = 0; i < 4; ++i)
                af[i] = *(const s16x8*)(As + (wm * 64 + i * 16 + l15) * 64 + ks * 32 + l4 * 8);
#pragma unroll
            for (int j = 0; j < 4; ++j)
                bf[j] = *(const s16x8*)(Bs + (wn * 64 + j * 16 + l15) * 64 + ks * 32 + l4 * 8);
#pragma unroll
            for (int i = 0; i < 4; ++i)
#pragma unroll
                for (int j = 0; j < 4; ++j)
                    acc[i][j] = __builtin_amdgcn_mfma_f32_16x16x32_bf16(
                        af[i], bf[j], acc[i][j], 0, 0, 0);
        }
    }

    if (MODE == 0) {
#pragma unroll
        for (int j = 0; j < 4; ++j) {
            int n = n0 + wn * 64 + j * 16 + l15;
            float bn = bias[n];
            int seg = n >> 10;
            int e = n & 1023;
            int hh = e >> 6, d = e & 63;
            float sc = (seg == 0) ? 0.125f : 1.0f;
#pragma unroll
            for (int i = 0; i < 4; ++i) {
                int mbase = m0 + wm * 64 + i * 16 + l4 * 4;
                int bb = mbase >> 10, sb = mbase & 1023;
                if (seg == 2) {
                    union { u16 u[4]; ushort4 s; } p;
#pragma unroll
                    for (int rr = 0; rr < 4; ++rr) p.u[rr] = f2bf(acc[i][j][rr] + bn);
                    *(ushort4*)(vt + ((size_t)(bb * 16 + hh) * 64 + d) * 1024 + sb) = p.s;
                } else {
                    u16* dst = (seg == 0) ? qb : kb;
#pragma unroll
                    for (int rr = 0; rr < 4; ++rr)
                        dst[((size_t)(bb * 16 + hh) * 1024 + sb + rr) * 64 + d] =
                            f2bf((acc[i][j][rr] + bn) * sc);
                }
            }
        }
    } else {
#pragma unroll
        for (int j = 0; j < 4; ++j) {
            int n = n0 + wn * 64 + j * 16 + l15;
            float bn = bias[n];
#pragma unroll
            for (int i = 0; i < 4; ++i) {
                int mbase = m0 + wm * 64 + i * 16 + l4 * 4;
#pragma unroll
                for (int rr = 0; rr < 4; ++rr)
                    outf[(size_t)(mbase + rr) * 1024 + n] = acc[i][j][rr] + bn;
            }
        }
    }
}

// ---------------------------------------------------------------------------
// build PV fragment from 8 exp-values (T12: cvt_pk + permlane32_swap).
// ---------------------------------------------------------------------------
template <int BASE>
__device__ __forceinline__ s16x8 build_pa(f32x16 e) {
    u32 a, bv, c, d;
    asm("v_cvt_pk_bf16_f32 %0, %1, %2" : "=v"(a) : "v"(e[BASE + 0]), "v"(e[BASE + 1]));
    asm("v_cvt_pk_bf16_f32 %0, %1, %2" : "=v"(bv) : "v"(e[BASE + 2]), "v"(e[BASE + 3]));
    asm("v_cvt_pk_bf16_f32 %0, %1, %2" : "=v"(c) : "v"(e[BASE + 4]), "v"(e[BASE + 5]));
    asm("v_cvt_pk_bf16_f32 %0, %1, %2" : "=v"(d) : "v"(e[BASE + 6]), "v"(e[BASE + 7]));
    asm("v_permlane32_swap_b32 %0, %1" : "+v"(a), "+v"(c));
    asm("v_permlane32_swap_b32 %0, %1" : "+v"(bv), "+v"(d));
    union { u32 w[4]; s16x8 v; } u;
    u.w[0] = a; u.w[1] = bv; u.w[2] = c; u.w[3] = d;
    return u.v;
}
__device__ __forceinline__ float pair_max(float v) {
    float a_ = v, b_ = v;
    asm("v_permlane32_swap_b32 %0, %1" : "+v"(a_), "+v"(b_));
    return fmaxf(a_, b_);
}
__device__ __forceinline__ float pair_sum(float v) {
    float a_ = v, b_ = v;
    asm("v_permlane32_swap_b32 %0, %1" : "+v"(a_), "+v"(b_));
    return a_ + b_;
}
__device__ __forceinline__ u32 pair_or(u32 v) {
    u32 a_ = v, b_ = v;
    asm("v_permlane32_swap_b32 %0, %1" : "+v"(a_), "+v"(b_));
    return a_ | b_;
}

// ---------------------------------------------------------------------------
// Flash attention v3: block = (b, h, 128 q-rows) = 4 waves sharing K/V.
// Per 64-row KV tile: stage K[64][64] + V^T[64][64] into LDS via
// global_load_lds (pre-swizzled source, XOR chunk swizzle), 2-barrier loop;
// each wave runs its own online softmax over its 32 q-rows.
// Swizzle: element at logical byte p stored at p ^ ((row&7)<<4).
// ---------------------------------------------------------------------------
__global__ __launch_bounds__(256, 4) void attn_flash(
    const u16* __restrict__ qg, const u16* __restrict__ kg,
    const u16* __restrict__ vtg, u16* __restrict__ og,
    float2* __restrict__ stats) {
    __shared__ __align__(16) u16 bufK[64 * 64];
    __shared__ __align__(16) u16 bufV[64 * 64];
    const int t = threadIdx.x;
    const int lane = t & 63;
    const int w = t >> 6;
    const int task = ((blockIdx.x & 7) << 7) | (blockIdx.x >> 3);  // XCD grouping
    const int b = task >> 7;
    const int h = (task >> 3) & 15;
    const int qg_ = task & 7;
    const int q = lane & 31;
    const int hi = lane >> 5;
    const int q0 = qg_ * 128 + w * 32;
    const size_t hb = (size_t)(b * 16 + h) << 16;   // * S * 64

    // staging lane mapping (inverse swizzle on the global source)
    const int lr = lane >> 3;                // 0..7: row within an issue
    const int lc = ((lane & 7) ^ lr) * 8;    // swizzled source col (elems)
    const int swz = (q & 7) << 4;            // read-side XOR (bytes)

    // Q fragments (pre-scaled by 1/8 in GEMM epilogue)
    s16x8 qf[4];
#pragma unroll
    for (int s = 0; s < 4; ++s)
        qf[s] = *(const s16x8*)(qg + hb + (size_t)(q0 + q) * 64 + s * 16 + hi * 8);

    f32x16 oLo = zero16(), oHi = zero16();
    float m = -1e30f, l = 0.f;

    for (int tile = 0; tile < 16; ++tile) {
        __syncthreads();                         // done reading previous tile
#pragma unroll
        for (int jj = 0; jj < 2; ++jj) {
            int j = w * 2 + jj;                  // 8 issues of 1KB per buffer
            gload16(kg + hb + (size_t)(tile * 64 + j * 8 + lr) * 64 + lc, bufK + j * 512);
            gload16(vtg + hb + (size_t)(j * 8 + lr) * 1024 + tile * 64 + lc, bufV + j * 512);
        }
        __syncthreads();                         // vmcnt drained -> tile ready
#pragma unroll
        for (int kk = 0; kk < 64; kk += 32) {
            // ---- K fragments (swizzled ds_read_b128) ----
            s16x8 ka[4];
#pragma unroll
            for (int s = 0; s < 4; ++s)
                ka[s] = *(const s16x8*)((const u8*)bufK +
                        ((((kk + q) << 7) + (s << 5) + (hi << 4)) ^ swz));
            f32x16 s_ = zero16();
#pragma unroll
            for (int s = 0; s < 4; ++s)
                s_ = __builtin_amdgcn_mfma_f32_32x32x16_bf16(ka[s], qf[s], s_, 0, 0, 0);
            // ---- tile max ----
            float m0 = fmaxf(fmaxf(s_[0], s_[4]), fmaxf(s_[8], s_[12]));
            float m1 = fmaxf(fmaxf(s_[1], s_[5]), fmaxf(s_[9], s_[13]));
            float m2 = fmaxf(fmaxf(s_[2], s_[6]), fmaxf(s_[10], s_[14]));
            float m3 = fmaxf(fmaxf(s_[3], s_[7]), fmaxf(s_[11], s_[15]));
            float pmax = pair_max(fmaxf(fmaxf(m0, m1), fmaxf(m2, m3)));
            // ---- branchless online rescale ----
            float mn = fmaxf(m, pmax);
            float r = __expf(m - mn);
            m = mn;
            // ---- exp + row-sum ----
            float s0 = 0.f, s1 = 0.f, s2 = 0.f, s3 = 0.f;
#pragma unroll
            for (int i = 0; i < 16; i += 4) {
                s_[i + 0] = __expf(s_[i + 0] - m);
                s_[i + 1] = __expf(s_[i + 1] - m);
                s_[i + 2] = __expf(s_[i + 2] - m);
                s_[i + 3] = __expf(s_[i + 3] - m);
                s0 += s_[i + 0]; s1 += s_[i + 1]; s2 += s_[i + 2]; s3 += s_[i + 3];
            }
            l = l * r + pair_sum((s0 + s1) + (s2 + s3));
            oLo = oLo * r;
            oHi = oHi * r;
            // ---- P fragments + PV: C[d][q] via A=V^T rows, B=P ----
            s16x8 p0 = build_pa<0>(s_), p1 = build_pa<8>(s_);
            s16x8 vLo0 = *(const s16x8*)((const u8*)bufV +
                         (((q << 7) + (kk << 1) + (hi << 4)) ^ swz));
            s16x8 vLo1 = *(const s16x8*)((const u8*)bufV +
                         (((q << 7) + (kk << 1) + 32 + (hi << 4)) ^ swz));
            s16x8 vHi0 = *(const s16x8*)((const u8*)bufV +
                         ((((q + 32) << 7) + (kk << 1) + (hi << 4)) ^ swz));
            s16x8 vHi1 = *(const s16x8*)((const u8*)bufV +
                         ((((q + 32) << 7) + (kk << 1) + 32 + (hi << 4)) ^ swz));
            oLo = __builtin_amdgcn_mfma_f32_32x32x16_bf16(vLo0, p0, oLo, 0, 0, 0);
            oLo = __builtin_amdgcn_mfma_f32_32x32x16_bf16(vLo1, p1, oLo, 0, 0, 0);
            oHi = __builtin_amdgcn_mfma_f32_32x32x16_bf16(vHi0, p0, oHi, 0, 0, 0);
            oHi = __builtin_amdgcn_mfma_f32_32x32x16_bf16(vHi1, p1, oHi, 0, 0, 0);
        }
    }
    // ---- normalize + store o (bf16) ----
    float inv = 1.0f / l;
    oLo = oLo * inv;
    oHi = oHi * inv;
    u16* orow = og + (size_t)(b * 1024 + q0 + q) * 1024 + h * 64;
#pragma unroll
    for (int rg = 0; rg < 4; ++rg) {
        union { u16 u[4]; u64 v; } pk;
#pragma unroll
        for (int j = 0; j < 4; ++j) pk.u[j] = f2bf(oLo[4 * rg + j]);
        *(u64*)(orow + 8 * rg + 4 * hi) = pk.v;
#pragma unroll
        for (int j = 0; j < 4; ++j) pk.u[j] = f2bf(oHi[4 * rg + j]);
        *(u64*)(orow + 32 + 8 * rg + 4 * hi) = pk.v;
    }
    if (hi == 0)
        stats[(size_t)(b * 16 + h) * 1024 + q0 + q] = make_float2(m, 0.0625f / l);
}

// ---------------------------------------------------------------------------
// attn_weights: one wave per (b, q-tile 32, k-slice 64), loops 16 heads.
// Pipelined K prefetch; applies exp(s-m)*inv16L with attn_flash's stats.
// ---------------------------------------------------------------------------
__global__ __launch_bounds__(256, 4) void attn_aw(
    const u16* __restrict__ qg, const u16* __restrict__ kg,
    const float2* __restrict__ stats, float* __restrict__ aw,
    u64* __restrict__ maskg) {
    const int t = threadIdx.x;
    const int lane = t & 63;
    const int bid = ((blockIdx.x & 7) << 7) | (blockIdx.x >> 3);  // XCD grouping
    const int wid = bid * 4 + (t >> 6);
    const int qt = wid & 31;
    const int ks = (wid >> 5) & 15;
    const int b = wid >> 9;
    const int q = lane & 31;
    const int hi = lane >> 5;
    const int q0 = qt * 32;
    const int kbase = ks * 64;

    f32x16 awA = zero16(), awB = zero16();

    s16x8 kc[4];
    {
        const u16* kp = kg + ((size_t)(b * 16) << 16) + (size_t)(kbase + q) * 64 + hi * 8;
#pragma unroll
        for (int s = 0; s < 4; ++s) kc[s] = *(const s16x8*)(kp + s * 16);
    }

    for (int h = 0; h < 16; ++h) {
        const size_t hb = (size_t)(b * 16 + h) << 16;
        s16x8 qf[4];
#pragma unroll
        for (int s = 0; s < 4; ++s)
            qf[s] = *(const s16x8*)(qg + hb + (size_t)(q0 + q) * 64 + s * 16 + hi * 8);
        float2 st = stats[(size_t)(b * 16 + h) * 1024 + q0 + q];
        s16x8 kn[4];
        {
            const u16* kp = kg + hb + (size_t)(kbase + 32 + q) * 64 + hi * 8;
#pragma unroll
            for (int s = 0; s < 4; ++s) kn[s] = *(const s16x8*)(kp + s * 16);
        }
        f32x16 s_ = zero16();
#pragma unroll
        for (int s = 0; s < 4; ++s)
            s_ = __builtin_amdgcn_mfma_f32_32x32x16_bf16(kc[s], qf[s], s_, 0, 0, 0);
#pragma unroll
        for (int i = 0; i < 16; ++i) awA[i] += __expf(s_[i] - st.x) * st.y;
#pragma unroll
        for (int s = 0; s < 4; ++s) kc[s] = kn[s];
        {
            const size_t hbn = (size_t)(b * 16 + ((h + 1) & 15)) << 16;
            const u16* kp = kg + hbn + (size_t)(kbase + q) * 64 + hi * 8;
#pragma unroll
            for (int s = 0; s < 4; ++s) kn[s] = *(const s16x8*)(kp + s * 16);
        }
        s_ = zero16();
#pragma unroll
        for (int s = 0; s < 4; ++s)
            s_ = __builtin_amdgcn_mfma_f32_32x32x16_bf16(kc[s], qf[s], s_, 0, 0, 0);
#pragma unroll
        for (int i = 0; i < 16; ++i) awB[i] += __expf(s_[i] - st.x) * st.y;
#pragma unroll
        for (int s = 0; s < 4; ++s) kc[s] = kn[s];
    }
    float* awrow = aw + (size_t)(b * 1024 + q0 + q) * 1024 + kbase;
#pragma unroll
    for (int rg = 0; rg < 4; ++rg) {
        *(float4*)(awrow + 8 * rg + 4 * hi) =
            make_float4(awA[4 * rg + 0], awA[4 * rg + 1], awA[4 * rg + 2], awA[4 * rg + 3]);
        *(float4*)(awrow + 32 + 8 * rg + 4 * hi) =
            make_float4(awB[4 * rg + 0], awB[4 * rg + 1], awB[4 * rg + 2], awB[4 * rg + 3]);
    }
    u32 lo = 0, hi32 = 0;
#pragma unroll
    for (int r = 0; r < 16; ++r) {
        int k = (r & 3) + 8 * (r >> 2) + 4 * hi;
        lo |= (awA[r] > 0.5f) ? (1u << k) : 0u;
        hi32 |= (awB[r] > 0.5f) ? (1u << k) : 0u;
    }
    lo = pair_or(lo);
    hi32 = pair_or(hi32);
    if (hi == 0)
        maskg[(size_t)(b * 1024 + q0 + q) * 16 + ks] = ((u64)hi32 << 32) | (u64)lo;
}

// ---------------------------------------------------------------------------
// Clustering: sequential greedy scan over NONEMPTY rows only.
// ---------------------------------------------------------------------------
__global__ __launch_bounds__(256) void cluster_kernel(
    const u64* __restrict__ maskg, float* __restrict__ cid, u64* __restrict__ cov) {
    __shared__ u64 mask[16384];
    __shared__ u16 rows[1024];
    const int t = threadIdx.x;
    const int b = blockIdx.x;
#pragma unroll
    for (int i = 0; i < 64; ++i)
        mask[t + 256 * i] = maskg[(size_t)b * 16384 + t + 256 * i];
#pragma unroll
    for (int i = 0; i < 4; ++i) cid[b * S + t + 256 * i] = -1.0f;
    __syncthreads();
    if (t < 64) {
        int nr = 0;
        for (int it = 0; it < 16; ++it) {
            int row = it * 64 + t;
            const u64* mp = mask + row * 16;
            u64 orv = 0;
#pragma unroll
            for (int j = 0; j < 16; ++j) orv |= mp[j];
            u64 bal = __ballot(orv != 0ULL);
            int pre = __popcll(bal & ((1ULL << t) - 1ULL));
            if (orv != 0ULL) rows[nr + pre] = (u16)row;
            nr += __popcll(bal);
        }
        u64 vis = 0;
        for (int idx = 0; idx < nr; ++idx) {
            int i = rows[idx];
            u64 viw = __shfl(vis, i >> 6);
            bool proc = ((viw >> (i & 63)) & 1ULL) == 0ULL;
            u64 cl = (proc && t < 16) ? mask[i * 16 + t] : 0ULL;
            u64 newly = cl & ~vis;
            vis |= cl;
            while (newly) {
                int bit = __ffsll((long long)newly) - 1;
                cid[b * S + t * 64 + bit] = (float)i;
                newly &= newly - 1;
            }
        }
        if (t < 16) cov[b * 16 + t] = vis;
    }
}

// ---------------------------------------------------------------------------
// clustered_outputs = covered ? x : -1e9
// ---------------------------------------------------------------------------
__global__ __launch_bounds__(256) void clustered_kernel(
    const float* __restrict__ x, const u64* __restrict__ cov,
    float* __restrict__ out2) {
    const size_t n4 = (size_t)B * S * E / 4;
    size_t idx = (size_t)blockIdx.x * 256 + threadIdx.x;
    const float4 neg = make_float4(-1e9f, -1e9f, -1e9f, -1e9f);
    for (; idx < n4; idx += (size_t)gridDim.x * 256) {
        size_t tok = idx >> 8;
        int bb = (int)(tok >> 10), s = (int)(tok & 1023);
        u64 m = cov[bb * 16 + (s >> 6)];
        bool c = ((m >> (s & 63)) & 1ULL) != 0ULL;
        float4 v = ((const float4*)x)[idx];
        ((float4*)out2)[idx] = c ? v : neg;
    }
}

extern "C" void kernel_launch(void* const* d_in, const int* in_sizes, int n_in,
                              void* d_out, int out_size, void* d_ws, size_t ws_size,
                              hipStream_t stream) {
    const float* x = (const float*)d_in[0];
    const float* w_in = (const float*)d_in[1];
    const float* b_in = (const float*)d_in[2];
    const float* w_out = (const float*)d_in[3];
    const float* b_out = (const float*)d_in[4];

    float* out0 = (float*)d_out;        // attn_output  [8,1024,1024]
    float* out1 = out0 + 8388608;       // attn_weights [8,1024,1024]
    float* out2 = out1 + 8388608;       // clustered    [8,1024,1024]
    float* out3 = out2 + 8388608;       // cluster_ids  [8,1024] (as float)

    // bf16 staging (each region dead before its final output is written):
    u16* q_bf = (u16*)out0;             // [B,H,S,64]  (dies at gemm<1>)
    u16* vt_bf = q_bf + 8388608;        // [B,H,64,S]  transposed V
    u16* xb = (u16*)out1;               // x bf16      (dies at attn_aw)
    u16* k_bf = (u16*)out2;             // [B,H,S,64]  (dies at clustered)
    u16* wb0 = k_bf + 8388608;          // W_in bf16
    u16* wb1 = wb0 + 3145728;           // W_out bf16
    float2* stats = (float2*)(k_bf + 12582912);  // {m, 1/(16 l)} per (b,h,q)
    u16* o_bf = (u16*)d_ws;             // attention output bf16 [B,S,E] (16 MB)
    u64* maskg = (u64*)((char*)d_ws + (size_t)(16u << 20));
    u64* cov = (u64*)((char*)d_ws + (size_t)(17u << 20));

    cvt_kernel<<<8192, 256, 0, stream>>>(x, xb, 2097152);
    cvt_kernel<<<3072, 256, 0, stream>>>(w_in, wb0, 786432);
    cvt_kernel<<<1024, 256, 0, stream>>>(w_out, wb1, 262144);

    mfma_gemm<0><<<dim3(64, 24), 256, 0, stream>>>(xb, wb0, b_in, q_bf, k_bf,
                                                   vt_bf, nullptr);
    attn_flash<<<1024, 256, 0, stream>>>(q_bf, k_bf, vt_bf, o_bf, stats);
    attn_aw<<<1024, 256, 0, stream>>>(q_bf, k_bf, stats, out1, maskg);
    mfma_gemm<1><<<dim3(64, 8), 256, 0, stream>>>(o_bf, wb1, b_out, nullptr,
                                                  nullptr, nullptr, out0);

    cluster_kernel<<<8, 256, 0, stream>>>(maskg, out3, cov);
    clustered_kernel<<<2048, 256, 0, stream>>>(x, cov, out2);
}